// Round 5
// baseline (3686.903 us; speedup 1.0000x reference)
//
#include <hip/hip_runtime.h>

#define NN 50000
#define EE 1600000
#define RR 16
#define NBASE 4
#define FINF 128
#define HD 128
#define NG 64
#define NCLS 2
#define NRSEG (NN*RR)   // 800000

typedef __attribute__((ext_vector_type(8))) short short8;
typedef __attribute__((ext_vector_type(4))) float f32x4;
typedef __attribute__((ext_vector_type(2))) float f32x2;
typedef unsigned short u16;
typedef unsigned int u32;
typedef unsigned long long u64;
typedef unsigned char u8;

__device__ __forceinline__ float bflo(u32 u){ return __builtin_bit_cast(float, u << 16); }
__device__ __forceinline__ float bfhi(u32 u){ return __builtin_bit_cast(float, u & 0xFFFF0000u); }
__device__ __forceinline__ u16 f2bf(float f){
  u32 u = __builtin_bit_cast(u32, f);
  u += 0x7FFFu + ((u >> 16) & 1u);
  return (u16)(u >> 16);
}
__device__ __forceinline__ u32 pack2(float a, float b){
  return (u32)f2bf(a) | ((u32)f2bf(b) << 16);
}
// HW packed f32->bf16 (RNE). No builtin on gfx950 (T12 recipe) -> inline asm.
__device__ __forceinline__ u32 cvt_pk_bf16(float a, float b){
  u32 r;
  asm("v_cvt_pk_bf16_f32 %0, %1, %2" : "=v"(r) : "v"(a), "v"(b));
  return r;
}
__device__ __forceinline__ float fastrcp(float x){
#if __has_builtin(__builtin_amdgcn_rcpf)
  return __builtin_amdgcn_rcpf(x);
#else
  return 1.0f / x;
#endif
}
__device__ __forceinline__ float ldf(const void* p, int i, int isbf){
  return isbf ? bflo((u32)((const u16*)p)[i]) : ((const float*)p)[i];
}

// ---------------- fp8 e4m3fn helpers (store paths clamp to +-448) ----------------
__device__ __forceinline__ float fp8_manual(u32 b){
  u32 s = (b>>7)&1, e = (b>>3)&15, m = b&7;
  float v;
  if (e==0) v = (float)m * 0.001953125f;
  else      v = __builtin_bit_cast(float, ((e+120u)<<23) | (m<<20));
  return s ? -v : v;
}
__device__ __forceinline__ u32 f32_to_fp8_manual(float f){
  u32 u = __builtin_bit_cast(u32, f);
  u32 s = u>>31;
  int e = (int)((u>>23)&0xFF);
  u32 m = u & 0x7FFFFF;
  int ee = e - 120;
  if (ee <= 0) return s<<7;
  u32 m3 = m >> 20, rem = m & 0xFFFFF;
  u32 rnd = (rem > 0x80000u) || (rem == 0x80000u && (m3 & 1));
  m3 += rnd;
  if (m3 == 8){ m3 = 0; ee += 1; }
  if (ee >= 16){ ee = 15; m3 = 6; }
  return (s<<7) | ((u32)ee<<3) | m3;
}
__device__ __forceinline__ void fp8x2_to_f32(u32 v, float& a, float& b){
#if __has_builtin(__builtin_amdgcn_cvt_pk_f32_fp8)
  f32x2 r = __builtin_amdgcn_cvt_pk_f32_fp8((int)v, false);
  a = r[0]; b = r[1];
#else
  a = fp8_manual(v & 0xFF); b = fp8_manual((v>>8)&0xFF);
#endif
}
__device__ __forceinline__ u32 pk_fp8x2(float a, float b){
  a = fminf(fmaxf(a, -448.f), 448.f);
  b = fminf(fmaxf(b, -448.f), 448.f);
#if __has_builtin(__builtin_amdgcn_cvt_pk_fp8_f32)
  return (u32)__builtin_amdgcn_cvt_pk_fp8_f32(a, b, 0, false) & 0xFFFF;
#else
  return f32_to_fp8_manual(a) | (f32_to_fp8_manual(b) << 8);
#endif
}

// ---------------- dtype detector ----------------
__global__ void k_detect(const u32* __restrict__ xw, int* __restrict__ flag){
  __shared__ int votes;
  if (threadIdx.x == 0) votes = 0;
  __syncthreads();
  u32 w = xw[threadIdx.x];
  int e = (w >> 7) & 0xFF;
  if (e >= 100 && e <= 129) atomicAdd(&votes, 1);
  __syncthreads();
  if (threadIdx.x == 0) flag[0] = (votes >= 192) ? 1 : 0;
}

// ---------------- quantize x -> fp8 copy (also zeroes cnt[] for k_hist) ----------
__global__ void k_quant(const void* __restrict__ src, u8* __restrict__ dstq,
                        const int* __restrict__ flagp, int* __restrict__ cnt){
  int i = blockIdx.x*256 + threadIdx.x;
  if (i < NRSEG) cnt[i] = 0;                 // replaces hipMemsetAsync
  if (i >= NN*HD/4) return;
  int isbf = flagp[0];
  float v0,v1,v2,v3;
  if (isbf){
    u32 a = ((const u32*)src)[i*2+0], b = ((const u32*)src)[i*2+1];
    v0=bflo(a); v1=bfhi(a); v2=bflo(b); v3=bfhi(b);
  } else {
    float4 f = ((const float4*)src)[i];
    v0=f.x; v1=f.y; v2=f.z; v3=f.w;
  }
  u32 q = pk_fp8x2(v0,v1) | (pk_fp8x2(v2,v3) << 16);
  ((u32*)dstq)[i] = q;
}

// ---------------- CSR build (REL-MAJOR: seg = rel*NN + dst) ----------------

__global__ void k_hist(const int* __restrict__ dst, const int* __restrict__ et,
                       int* __restrict__ cnt){
  int e = blockIdx.x*256 + threadIdx.x;
  if (e < EE) atomicAdd(&cnt[et[e]*NN + dst[e]], 1);
}

#define SCB 1024
__global__ __launch_bounds__(SCB) void k_scan1(const int* __restrict__ cnt,
                                               int* __restrict__ off,
                                               int* __restrict__ bsum){
  __shared__ int sh[SCB];
  int tid = threadIdx.x;
  int i = blockIdx.x*SCB + tid;
  int v = (i < NRSEG) ? cnt[i] : 0;
  sh[tid] = v; __syncthreads();
  for (int d=1; d<SCB; d<<=1){
    int t = (tid >= d) ? sh[tid-d] : 0;
    __syncthreads();
    sh[tid] += t;
    __syncthreads();
  }
  if (i < NRSEG) off[i] = sh[tid] - v;
  if (tid == SCB-1) bsum[blockIdx.x] = sh[SCB-1];
}

__global__ __launch_bounds__(1024) void k_scan2(int* __restrict__ bsum, int nb){
  __shared__ int sh[1024];
  __shared__ int carry;
  int tid = threadIdx.x;
  if (tid == 0) carry = 0;
  __syncthreads();
  for (int base=0; base<nb; base+=1024){
    int i = base + tid;
    int v = (i < nb) ? bsum[i] : 0;
    int orig = v;
    sh[tid] = v; __syncthreads();
    for (int d=1; d<1024; d<<=1){
      int t = (tid >= d) ? sh[tid-d] : 0;
      __syncthreads();
      sh[tid] += t;
      __syncthreads();
    }
    int total = sh[1023];
    int excl = sh[tid] - orig + carry;
    if (i < nb) bsum[i] = excl;
    __syncthreads();
    if (tid == 0) carry += total;
    __syncthreads();
  }
}

__global__ __launch_bounds__(SCB) void k_scan3(const int* __restrict__ cnt,
                                               int* __restrict__ off,
                                               const int* __restrict__ bsum){
  int i = blockIdx.x*SCB + threadIdx.x;
  if (i < NRSEG){
    int o = off[i] + bsum[blockIdx.x];
    off[i] = o;
    if (i == NRSEG-1) off[NRSEG] = o + cnt[i];
  }
}

// NOTE: stores src*128 (pre-shifted byte offset into xq) -- k_layer uses directly
__global__ void k_scatter(const int* __restrict__ src, const int* __restrict__ dst,
                          const int* __restrict__ et, const int* __restrict__ off,
                          int* __restrict__ cnt, int* __restrict__ esrc){
  int e = blockIdx.x*256 + threadIdx.x;
  if (e < EE){
    int seg = et[e]*NN + dst[e];
    int p = atomicSub(&cnt[seg], 1) - 1;
    esrc[off[seg] + p] = src[e] << 7;
  }
}

// ---- weights (bf16, FRAGMENT-SWIZZLED, R11-proven) — all 3 layers fused ----

__global__ void k_weights3(const void* __restrict__ b0, const void* __restrict__ c0,
                           const void* __restrict__ r0,
                           const void* __restrict__ b1, const void* __restrict__ c1,
                           const void* __restrict__ r1,
                           const void* __restrict__ b2, const void* __restrict__ c2,
                           const void* __restrict__ r2,
                           u16* __restrict__ WTf, const int* __restrict__ flagp){
  int gid = blockIdx.x;
  int layer = gid / 1088;
  int blk = gid - layer*1088;
  int idx = blk*256 + threadIdx.x;
  if (idx >= 17*16384) return;
  const void* bases = (layer==0) ? b0 : (layer==1) ? b1 : b2;
  const void* comp  = (layer==0) ? c0 : (layer==1) ? c1 : c2;
  const void* root  = (layer==0) ? r0 : (layer==1) ? r1 : r2;
  u16* W = WTf + (u32)layer * (17*16384);
  int isbf = flagp[0];
  int r = idx >> 14;
  int o = (idx >> 7) & 127;
  int i = idx & 127;
  float v;
  if (r < RR){
    v = 0.f;
    #pragma unroll
    for (int b=0;b<NBASE;b++)
      v += ldf(comp, r*NBASE+b, isbf) * ldf(bases, (b*FINF + i)*HD + o, isbf);
  } else {
    v = ldf(root, i*HD + o, isbf);
  }
  int wv = o >> 5, ct = (o >> 4) & 1, mrow = o & 15;
  int ks = i >> 5, quad = (i >> 3) & 3, j = i & 7;
  int lane = quad*16 + mrow;
  W[(u32)((((r*4+wv)*2+ct)*4+ks)*64 + lane)*8 + j] = f2bf(v);
}

// ---------------- fused aggregate + GEMM layer ----------------
// v16: LDS-atomic aggregation. The serial per-edge consume/flush chain
// (data-dependent while/doflush branches -- common to v12/v13/v15, all ~125us)
// is replaced by: per-lane node-id vector (branch-free compare-scan), then per
// edge {readlane node, fp8 cvt, 2x ds_add_f32 into a per-wave f32 slab}.
// Zero data-dependent branches. Finalize = straight-line 16-node unroll:
// read slab, scale by rcp(cnt), cvt_pk, write Abuf (which ALIASES the slab
// head; node-k write region always below node-k+1 read region -- safe).
// LDS 33.9KB -> 4 blocks/CU. Loads = v15's proven asm-batched gather.

#define TN 16

#define GLD(rg, kk) { u32 voff_ = (u32)__builtin_amdgcn_readlane(eidv, eb+(kk)) + lane2u; \
  asm volatile("global_load_ushort %0, %1, %2" : "=v"(rg) : "v"(voff_), "s"(xq)); }
#define WAITV0 { asm volatile("s_waitcnt vmcnt(0)" ::: "memory"); \
  __builtin_amdgcn_sched_barrier(0); }
// consume edge (eb+kk): route into Facc[wv][node][lane*2 .. +1]
#define CNS(rg, kk) { int nl_ = __builtin_amdgcn_readlane(nlv, eb+(kk)); \
  float* fp_ = FaccW + nl_*128 + (lane<<1); \
  float da_, db_; fp8x2_to_f32(rg, da_, db_); \
  atomicAdd(fp_, da_); atomicAdd(fp_+1, db_); }
#define CNSG(rg, kk) if (eb+(kk) < bl) CNS(rg, kk)

__global__ __launch_bounds__(256, 4) void k_layer(
    const u8*  __restrict__ xq,            // fp8 input (gather + root)
    const u16* __restrict__ WTf,
    const void* __restrict__ bias, const int* __restrict__ off,
    const int* __restrict__ esrc,          // values are src*128 (byte offsets)
    u16* __restrict__ hout,                // bf16 out (iff write_bf)
    u8* __restrict__ hq,                   // fp8 out (iff !write_bf)
    const int* __restrict__ flagp, int write_bf, int relu)
{
  // per-wave slab: 2048 f32 = [16 nodes][128 feats]; Abuf (16x136 u16 = 4352B)
  // aliases the slab head for the MFMA phase.
  __shared__ __align__(16) float Facc[4][2048];  // 32768 B
  __shared__ int soff[RR*17];                    // 1088 B
  int tid = threadIdx.x;
  int n0 = blockIdx.x * TN;
  int isbf_in = flagp[0];

  int wv = tid >> 6;
  int lane = tid & 63;
  u32 lane2u = (u32)(lane << 1);
  int mrow = lane & 15;
  int quad = lane >> 4;
  float* FaccW = &Facc[wv][0];

  // ---- stage off window: soff[r*17+k] = off[r*NN + n0 + k], k=0..16 ----
  for (int i = tid; i < RR*17; i += 256){
    int r = i / 17, k = i - r*17;
    soff[i] = off[r*NN + n0 + k];
  }
  __syncthreads();

  f32x4 acc[2];
  { f32x4 z = {0.f,0.f,0.f,0.f}; acc[0] = z; acc[1] = z; }

  for (int t=0; t<4; ++t){
    int r = t*4 + wv;
    int offv = 0;
    if (lane <= 16) offv = soff[r*17 + lane];
    int ws = __builtin_amdgcn_readlane(offv, 0);
    int we = __builtin_amdgcn_readlane(offv, 16);
    int blen = we - ws;

    // ---- zero own slab (2048 f32 / 64 lanes = 8 x b128 per lane) ----
    {
      f32x4 z = {0.f,0.f,0.f,0.f};
      float* zp = FaccW + lane*4;
      #pragma unroll
      for (int k=0;k<8;k++) *(f32x4*)(zp + k*256) = z;
    }

    // ---- gather + LDS-atomic accumulate ----
    if (blen > 0){
      for (int base = 0; base < blen; base += 64){
        int bl = blen - base; if (bl > 64) bl = 64;
        int ecl = bl - 1;
        // 64 edge byte-offsets, lanes >= bl duplicate the last (safe dup loads)
        int eidv = esrc[ws + base + (lane < ecl ? lane : ecl)];
        // per-lane node index of edge (ws+base+lane): branch-free compare-scan
        int eg = ws + base + lane;
        int nlv = 0;
        #pragma unroll
        for (int k=1;k<16;k++){
          int bk = __builtin_amdgcn_readlane(offv, k);
          nlv += (eg >= bk) ? 1 : 0;
        }
        for (int eb = 0; eb < bl; eb += 16){
          u32 g0,g1,g2,g3,g4,g5,g6,g7,g8,g9,g10,g11,g12,g13,g14,g15;
          GLD(g0,0) GLD(g1,1) GLD(g2,2) GLD(g3,3)
          GLD(g4,4) GLD(g5,5) GLD(g6,6) GLD(g7,7)
          GLD(g8,8) GLD(g9,9) GLD(g10,10) GLD(g11,11)
          GLD(g12,12) GLD(g13,13) GLD(g14,14) GLD(g15,15)
          WAITV0
          if (eb + 16 <= bl){
            CNS(g0,0) CNS(g1,1) CNS(g2,2) CNS(g3,3)
            CNS(g4,4) CNS(g5,5) CNS(g6,6) CNS(g7,7)
            CNS(g8,8) CNS(g9,9) CNS(g10,10) CNS(g11,11)
            CNS(g12,12) CNS(g13,13) CNS(g14,14) CNS(g15,15)
          } else {
            CNSG(g0,0) CNSG(g1,1) CNSG(g2,2) CNSG(g3,3)
            CNSG(g4,4) CNSG(g5,5) CNSG(g6,6) CNSG(g7,7)
            CNSG(g8,8) CNSG(g9,9) CNSG(g10,10) CNSG(g11,11)
            CNSG(g12,12) CNSG(g13,13) CNSG(g14,14) CNSG(g15,15)
          }
        }
      }
    }

    // ---- finalize own slab: mean + bf16 pack into Abuf (aliases slab head) ----
    // half A: nodes 0..7 (reads at bytes >= 0, writes end <= 2176 < node-8 read
    // at 4096); half B: nodes 8..15 (writes end <= 4352 <= reads done first).
    {
      u16* abase = (u16*)FaccW + lane*2;
      float* rbase = FaccW + lane*2;
      f32x2 d0,d1,d2,d3,d4,d5,d6,d7;
      #define RDN(dk, k) dk = *(f32x2*)(rbase + (k)*128);
      #define WRN(dk, k) { \
        int c_ = __builtin_amdgcn_readlane(offv, (k)+1) - __builtin_amdgcn_readlane(offv, (k)); \
        float inv_ = fastrcp((float)(c_ > 0 ? c_ : 1)); \
        *(u32*)(abase + (k)*136) = cvt_pk_bf16(dk[0]*inv_, dk[1]*inv_); }
      RDN(d0,0) RDN(d1,1) RDN(d2,2) RDN(d3,3)
      RDN(d4,4) RDN(d5,5) RDN(d6,6) RDN(d7,7)
      WRN(d0,0) WRN(d1,1) WRN(d2,2) WRN(d3,3)
      WRN(d4,4) WRN(d5,5) WRN(d6,6) WRN(d7,7)
      RDN(d0,8) RDN(d1,9) RDN(d2,10) RDN(d3,11)
      RDN(d4,12) RDN(d5,13) RDN(d6,14) RDN(d7,15)
      WRN(d0,8) WRN(d1,9) WRN(d2,10) WRN(d3,11)
      WRN(d4,12) WRN(d5,13) WRN(d6,14) WRN(d7,15)
      #undef RDN
      #undef WRN
    }
    __syncthreads();

    // ---- MFMA: 4 staged relations; wave wv owns cols [32wv, 32wv+32) ----
    #pragma unroll
    for (int rloc=0; rloc<4; ++rloc){
      int rr = t*4 + rloc;
      const u16* Ab = (const u16*)&Facc[rloc][0];
      const u16* Bp = WTf + (u32)(((rr*4 + wv)*2)*4*64)*8 + (u32)lane*8;
      #pragma unroll
      for (int ks=0; ks<4; ++ks){
        short8 af = *(const short8*)(Ab + mrow*136 + ks*32 + quad*8);
        #pragma unroll
        for (int ct=0; ct<2; ++ct){
          short8 bf = *(const short8*)(Bp + (u32)(ct*4 + ks)*64*8);
          acc[ct] = __builtin_amdgcn_mfma_f32_16x16x32_bf16(af, bf, acc[ct], 0, 0, 0);
        }
      }
    }
    __syncthreads();   // A slabs free for next round's zero+atomics
  }
  // ---- root pass: barrier-free, A-frags direct from xq (L2-hot 2KB region) ----
  {
    const u8* xrow = xq + (u32)(n0 + mrow)*HD;
    const u16* Bp = WTf + (u32)(((16*4 + wv)*2)*4*64)*8 + (u32)lane*8;
    #pragma unroll
    for (int ks=0; ks<4; ++ks){
      u32 lo = *(const u32*)(xrow + ks*32 + quad*8);
      u32 hi = *(const u32*)(xrow + ks*32 + quad*8 + 4);
      float f0,f1,f2,f3,f4,f5,f6,f7;
      fp8x2_to_f32(lo & 0xFFFFu, f0, f1);
      fp8x2_to_f32(lo >> 16,     f2, f3);
      fp8x2_to_f32(hi & 0xFFFFu, f4, f5);
      fp8x2_to_f32(hi >> 16,     f6, f7);
      union { short8 v; u32 w[4]; } u;
      u.w[0] = cvt_pk_bf16(f0,f1); u.w[1] = cvt_pk_bf16(f2,f3);
      u.w[2] = cvt_pk_bf16(f4,f5); u.w[3] = cvt_pk_bf16(f6,f7);
      #pragma unroll
      for (int ct=0; ct<2; ++ct){
        short8 bf = *(const short8*)(Bp + (u32)(ct*4 + ks)*64*8);
        acc[ct] = __builtin_amdgcn_mfma_f32_16x16x32_bf16(u.v, bf, acc[ct], 0, 0, 0);
      }
    }
  }
  // ---- epilogue: node = n0 + quad*4 + rg; col = wv*32 + ct*16 + mrow ----
  #pragma unroll
  for (int ct=0; ct<2; ++ct){
    int col = wv*32 + ct*16 + mrow;
    float bv = ldf(bias, col, isbf_in);
    #pragma unroll
    for (int rg=0; rg<4; ++rg){
      int n = n0 + quad*4 + rg;
      float v = acc[ct][rg] + bv;
      if (relu) v = fmaxf(v, 0.f);
      if (!(v == v)) v = 0.f;
      if (write_bf) hout[(u32)(n*HD + col)] = f2bf(v);
      else          hq[(u32)(n*HD + col)] = (u8)(pk_fp8x2(v, 0.f) & 0xFF);
    }
  }
}

// ---------------- global mean pool (bf16 h) + concat + linear head ----------------

__global__ __launch_bounds__(1024) void k_pool_head(
    const u16* __restrict__ h, const int* __restrict__ batch,
    const int* __restrict__ rlab, const void* __restrict__ rel_emb,
    const void* __restrict__ lin_w, const void* __restrict__ lin_b,
    void* __restrict__ out, const int* __restrict__ flagp)
{
  int g = blockIdx.x;
  int isbf = flagp[0];
  __shared__ int bounds[2];
  __shared__ float psum[8][128];
  __shared__ float red[4];
  if (threadIdx.x == 0){
    int lo=0, hi=NN;
    while (lo < hi){ int m=(lo+hi)>>1; if (batch[m] < g) lo=m+1; else hi=m; }
    bounds[0] = lo;
    int lo2=lo, hi2=NN;
    while (lo2 < hi2){ int m=(lo2+hi2)>>1; if (batch[m] < g+1) lo2=m+1; else hi2=m; }
    bounds[1] = lo2;
  }
  __syncthreads();
  int lo = bounds[0], hi = bounds[1];
  int f = threadIdx.x & 127;
  int s = threadIdx.x >> 7;          // 0..7
  float acc = 0.f;
  for (int n = lo + s; n < hi; n += 8) acc += bflo((u32)h[(u32)(n*HD + f)]);
  psum[s][f] = acc;
  __syncthreads();
  if (threadIdx.x < 128){
    int cn = hi - lo;
    float tot = 0.f;
    #pragma unroll
    for (int k=0;k<8;k++) tot += psum[k][f];
    float pooled = tot / (float)(cn > 0 ? cn : 1);
    int rl = rlab[g];
    float re = ldf(rel_emb, rl*HD + f, isbf);
    float v0 = pooled * ldf(lin_w, f*NCLS+0, isbf) + re * ldf(lin_w, (HD+f)*NCLS+0, isbf);
    float v1 = pooled * ldf(lin_w, f*NCLS+1, isbf) + re * ldf(lin_w, (HD+f)*NCLS+1, isbf);
    #pragma unroll
    for (int o=32;o>0;o>>=1){ v0 += __shfl_down(v0,o); v1 += __shfl_down(v1,o); }
    int ln = threadIdx.x & 63, wvv = threadIdx.x >> 6;
    if (ln == 0){ red[wvv*2] = v0; red[wvv*2+1] = v1; }
  }
  __syncthreads();
  if (threadIdx.x == 0){
    float o0 = red[0] + red[2] + ldf(lin_b, 0, isbf);
    float o1 = red[1] + red[3] + ldf(lin_b, 1, isbf);
    if (isbf){
      ((u16*)out)[g*NCLS+0] = f2bf(o0);
      ((u16*)out)[g*NCLS+1] = f2bf(o1);
    } else {
      ((float*)out)[g*NCLS+0] = o0;
      ((float*)out)[g*NCLS+1] = o1;
    }
  }
}

// ---------------- launch ----------------
// ws: flag 256B + off 3.2MB + esrc 6.4MB + WTf3 1.67MB + xq/h1q/h2q 6.4MB x3 +
// h3 12.8MB = 43.3 MB (< 45.37 proven-safe). cnt+bsum alias inside h3.

extern "C" void kernel_launch(void* const* d_in, const int* in_sizes, int n_in,
                              void* d_out, int out_size, void* d_ws, size_t ws_size,
                              hipStream_t stream)
{
  (void)in_sizes; (void)n_in; (void)out_size; (void)ws_size;
  const void* x      = d_in[0];
  const int* eidx    = (const int*)d_in[1];
  const int* etype   = (const int*)d_in[2];
  const int* batch   = (const int*)d_in[3];
  const int* rlab    = (const int*)d_in[4];
  const void* rel_emb = d_in[6];
  const void* basesA[3] = {d_in[7],  d_in[11], d_in[15]};
  const void* compA[3]  = {d_in[8],  d_in[12], d_in[16]};
  const void* rootA[3]  = {d_in[9],  d_in[13], d_in[17]};
  const void* biasA[3]  = {d_in[10], d_in[14], d_in[18]};
  const void* lin_w  = d_in[19];
  const void* lin_b  = d_in[20];

  char* p = (char*)d_ws;
  auto alloc = [&](size_t bytes)->char*{ char* r = p; p += (bytes + 255) & ~(size_t)255; return r; };
  int*   flag   = (int*)  alloc(256);
  int*   off    = (int*)  alloc((size_t)(NRSEG+1)*4);
  int*   esrc   = (int*)  alloc((size_t)(EE+64)*4);
  u16*   WTf    = (u16*)  alloc((size_t)3*17*16384*2);
  u8*    xq     = (u8*)   alloc((size_t)NN*HD);
  u8*    h1q    = (u8*)   alloc((size_t)NN*HD);
  u8*    h2q    = (u8*)   alloc((size_t)NN*HD);
  u16*   h3     = (u16*)  alloc((size_t)NN*HD*2);
  int*   cnt    = (int*)h3;
  int*   bsum   = (int*)((char*)h3 + (size_t)NRSEG*4);

  const int* src_in = eidx;        // edge_index[0]
  const int* dst_in = eidx + EE;   // edge_index[1]

  const int nscan = (NRSEG + SCB - 1) / SCB;   // 782

  k_detect <<<1, 256, 0, stream>>>((const u32*)x, flag);
  k_quant  <<<(NN*HD/4 + 255)/256, 256, 0, stream>>>(x, xq, flag, cnt);
  k_hist   <<<EE/256, 256, 0, stream>>>(dst_in, etype, cnt);
  k_scan1  <<<nscan, SCB, 0, stream>>>(cnt, off, bsum);
  k_scan2  <<<1,    1024, 0, stream>>>(bsum, nscan);
  k_scan3  <<<nscan, SCB, 0, stream>>>(cnt, off, bsum);
  k_scatter<<<EE/256, 256, 0, stream>>>(src_in, dst_in, etype, off, cnt, esrc);

  k_weights3<<<3*1088, 256, 0, stream>>>(basesA[0], compA[0], rootA[0],
                                         basesA[1], compA[1], rootA[1],
                                         basesA[2], compA[2], rootA[2],
                                         WTf, flag);

  const int nblk = NN / TN;   // 3125, exact
  u16* W0 = WTf;
  u16* W1 = WTf + (size_t)1*17*16384;
  u16* W2 = WTf + (size_t)2*17*16384;
  // layer 1: xq -> h1q (fp8)
  k_layer<<<nblk, 256, 0, stream>>>(xq,  W0, biasA[0], off, esrc, (u16*)0, h1q, flag, 0, 1);
  // layer 2: h1q -> h2q (fp8)
  k_layer<<<nblk, 256, 0, stream>>>(h1q, W1, biasA[1], off, esrc, (u16*)0, h2q, flag, 0, 1);
  // layer 3: h2q -> h3 (bf16, no relu)
  k_layer<<<nblk, 256, 0, stream>>>(h2q, W2, biasA[2], off, esrc, h3, (u8*)0, flag, 1, 0);

  k_pool_head<<<NG, 1024, 0, stream>>>(h3, batch, rlab, rel_emb, lin_w, lin_b,
                                       d_out, flag);
}

// Round 6
// 660.826 us; speedup vs baseline: 5.5792x; 5.5792x over previous
//
#include <hip/hip_runtime.h>

#define NN 50000
#define EE 1600000
#define RR 16
#define NBASE 4
#define FINF 128
#define HD 128
#define NG 64
#define NCLS 2
#define NRSEG (NN*RR)   // 800000

typedef __attribute__((ext_vector_type(8))) short short8;
typedef __attribute__((ext_vector_type(4))) float f32x4;
typedef __attribute__((ext_vector_type(2))) float f32x2;
typedef unsigned short u16;
typedef unsigned int u32;
typedef unsigned long long u64;
typedef unsigned char u8;

__device__ __forceinline__ float bflo(u32 u){ return __builtin_bit_cast(float, u << 16); }
__device__ __forceinline__ float bfhi(u32 u){ return __builtin_bit_cast(float, u & 0xFFFF0000u); }
__device__ __forceinline__ u16 f2bf(float f){
  u32 u = __builtin_bit_cast(u32, f);
  u += 0x7FFFu + ((u >> 16) & 1u);
  return (u16)(u >> 16);
}
// HW packed f32->bf16 (RNE). No builtin on gfx950 (T12 recipe) -> inline asm.
__device__ __forceinline__ u32 cvt_pk_bf16(float a, float b){
  u32 r;
  asm("v_cvt_pk_bf16_f32 %0, %1, %2" : "=v"(r) : "v"(a), "v"(b));
  return r;
}
__device__ __forceinline__ float fastrcp(float x){
#if __has_builtin(__builtin_amdgcn_rcpf)
  return __builtin_amdgcn_rcpf(x);
#else
  return 1.0f / x;
#endif
}
__device__ __forceinline__ float ldf(const void* p, int i, int isbf){
  return isbf ? bflo((u32)((const u16*)p)[i]) : ((const float*)p)[i];
}

// ---------------- fp8 e4m3fn helpers (store paths clamp to +-448) ----------------
__device__ __forceinline__ float fp8_manual(u32 b){
  u32 s = (b>>7)&1, e = (b>>3)&15, m = b&7;
  float v;
  if (e==0) v = (float)m * 0.001953125f;
  else      v = __builtin_bit_cast(float, ((e+120u)<<23) | (m<<20));
  return s ? -v : v;
}
__device__ __forceinline__ u32 f32_to_fp8_manual(float f){
  u32 u = __builtin_bit_cast(u32, f);
  u32 s = u>>31;
  int e = (int)((u>>23)&0xFF);
  u32 m = u & 0x7FFFFF;
  int ee = e - 120;
  if (ee <= 0) return s<<7;
  u32 m3 = m >> 20, rem = m & 0xFFFFF;
  u32 rnd = (rem > 0x80000u) || (rem == 0x80000u && (m3 & 1));
  m3 += rnd;
  if (m3 == 8){ m3 = 0; ee += 1; }
  if (ee >= 16){ ee = 15; m3 = 6; }
  return (s<<7) | ((u32)ee<<3) | m3;
}
__device__ __forceinline__ void fp8x2_to_f32(u32 v, float& a, float& b){
#if __has_builtin(__builtin_amdgcn_cvt_pk_f32_fp8)
  f32x2 r = __builtin_amdgcn_cvt_pk_f32_fp8((int)v, false);
  a = r[0]; b = r[1];
#else
  a = fp8_manual(v & 0xFF); b = fp8_manual((v>>8)&0xFF);
#endif
}
__device__ __forceinline__ u32 pk_fp8x2(float a, float b){
  a = fminf(fmaxf(a, -448.f), 448.f);
  b = fminf(fmaxf(b, -448.f), 448.f);
#if __has_builtin(__builtin_amdgcn_cvt_pk_fp8_f32)
  return (u32)__builtin_amdgcn_cvt_pk_fp8_f32(a, b, 0, false) & 0xFFFF;
#else
  return f32_to_fp8_manual(a) | (f32_to_fp8_manual(b) << 8);
#endif
}

// ---------------- dtype detector ----------------
__global__ void k_detect(const u32* __restrict__ xw, int* __restrict__ flag){
  __shared__ int votes;
  if (threadIdx.x == 0) votes = 0;
  __syncthreads();
  u32 w = xw[threadIdx.x];
  int e = (w >> 7) & 0xFF;
  if (e >= 100 && e <= 129) atomicAdd(&votes, 1);
  __syncthreads();
  if (threadIdx.x == 0) flag[0] = (votes >= 192) ? 1 : 0;
}

// ---------------- quantize x -> fp8 copy (also zeroes cnt[] for k_hist) ----------
__global__ void k_quant(const void* __restrict__ src, u8* __restrict__ dstq,
                        const int* __restrict__ flagp, int* __restrict__ cnt){
  int i = blockIdx.x*256 + threadIdx.x;
  if (i < NRSEG) cnt[i] = 0;                 // replaces hipMemsetAsync
  if (i >= NN*HD/4) return;
  int isbf = flagp[0];
  float v0,v1,v2,v3;
  if (isbf){
    u32 a = ((const u32*)src)[i*2+0], b = ((const u32*)src)[i*2+1];
    v0=bflo(a); v1=bfhi(a); v2=bflo(b); v3=bfhi(b);
  } else {
    float4 f = ((const float4*)src)[i];
    v0=f.x; v1=f.y; v2=f.z; v3=f.w;
  }
  u32 q = pk_fp8x2(v0,v1) | (pk_fp8x2(v2,v3) << 16);
  ((u32*)dstq)[i] = q;
}

// ---------------- CSR build (REL-MAJOR: seg = rel*NN + dst) ----------------

__global__ void k_hist(const int* __restrict__ dst, const int* __restrict__ et,
                       int* __restrict__ cnt){
  int e = blockIdx.x*256 + threadIdx.x;
  if (e < EE) atomicAdd(&cnt[et[e]*NN + dst[e]], 1);
}

#define SCB 1024
__global__ __launch_bounds__(SCB) void k_scan1(const int* __restrict__ cnt,
                                               int* __restrict__ off,
                                               int* __restrict__ bsum){
  __shared__ int sh[SCB];
  int tid = threadIdx.x;
  int i = blockIdx.x*SCB + tid;
  int v = (i < NRSEG) ? cnt[i] : 0;
  sh[tid] = v; __syncthreads();
  for (int d=1; d<SCB; d<<=1){
    int t = (tid >= d) ? sh[tid-d] : 0;
    __syncthreads();
    sh[tid] += t;
    __syncthreads();
  }
  if (i < NRSEG) off[i] = sh[tid] - v;
  if (tid == SCB-1) bsum[blockIdx.x] = sh[SCB-1];
}

__global__ __launch_bounds__(1024) void k_scan2(int* __restrict__ bsum, int nb){
  __shared__ int sh[1024];
  __shared__ int carry;
  int tid = threadIdx.x;
  if (tid == 0) carry = 0;
  __syncthreads();
  for (int base=0; base<nb; base+=1024){
    int i = base + tid;
    int v = (i < nb) ? bsum[i] : 0;
    int orig = v;
    sh[tid] = v; __syncthreads();
    for (int d=1; d<1024; d<<=1){
      int t = (tid >= d) ? sh[tid-d] : 0;
      __syncthreads();
      sh[tid] += t;
      __syncthreads();
    }
    int total = sh[1023];
    int excl = sh[tid] - orig + carry;
    if (i < nb) bsum[i] = excl;
    __syncthreads();
    if (tid == 0) carry += total;
    __syncthreads();
  }
}

__global__ __launch_bounds__(SCB) void k_scan3(const int* __restrict__ cnt,
                                               int* __restrict__ off,
                                               const int* __restrict__ bsum){
  int i = blockIdx.x*SCB + threadIdx.x;
  if (i < NRSEG){
    int o = off[i] + bsum[blockIdx.x];
    off[i] = o;
    if (i == NRSEG-1) off[NRSEG] = o + cnt[i];
  }
}

// NOTE: stores src*128 (pre-shifted byte offset into xq) -- k_layer uses directly
__global__ void k_scatter(const int* __restrict__ src, const int* __restrict__ dst,
                          const int* __restrict__ et, const int* __restrict__ off,
                          int* __restrict__ cnt, int* __restrict__ esrc){
  int e = blockIdx.x*256 + threadIdx.x;
  if (e < EE){
    int seg = et[e]*NN + dst[e];
    int p = atomicSub(&cnt[seg], 1) - 1;
    esrc[off[seg] + p] = src[e] << 7;
  }
}

// ---- weights (bf16, FRAGMENT-SWIZZLED, R11-proven) — all 3 layers fused ----

__global__ void k_weights3(const void* __restrict__ b0, const void* __restrict__ c0,
                           const void* __restrict__ r0,
                           const void* __restrict__ b1, const void* __restrict__ c1,
                           const void* __restrict__ r1,
                           const void* __restrict__ b2, const void* __restrict__ c2,
                           const void* __restrict__ r2,
                           u16* __restrict__ WTf, const int* __restrict__ flagp){
  int gid = blockIdx.x;
  int layer = gid / 1088;
  int blk = gid - layer*1088;
  int idx = blk*256 + threadIdx.x;
  if (idx >= 17*16384) return;
  const void* bases = (layer==0) ? b0 : (layer==1) ? b1 : b2;
  const void* comp  = (layer==0) ? c0 : (layer==1) ? c1 : c2;
  const void* root  = (layer==0) ? r0 : (layer==1) ? r1 : r2;
  u16* W = WTf + (u32)layer * (17*16384);
  int isbf = flagp[0];
  int r = idx >> 14;
  int o = (idx >> 7) & 127;
  int i = idx & 127;
  float v;
  if (r < RR){
    v = 0.f;
    #pragma unroll
    for (int b=0;b<NBASE;b++)
      v += ldf(comp, r*NBASE+b, isbf) * ldf(bases, (b*FINF + i)*HD + o, isbf);
  } else {
    v = ldf(root, i*HD + o, isbf);
  }
  int wv = o >> 5, ct = (o >> 4) & 1, mrow = o & 15;
  int ks = i >> 5, quad = (i >> 3) & 3, j = i & 7;
  int lane = quad*16 + mrow;
  W[(u32)((((r*4+wv)*2+ct)*4+ks)*64 + lane)*8 + j] = f2bf(v);
}

// ---------------- fused aggregate + GEMM layer ----------------
// v17: TN=32 (was 16) to halve B-fragment L2 traffic -- the missed budget item:
// per block per layer every wave streams its 32-col slice of all 17 weight
// matrices from global (557KB/block); at 3125 blocks that's 1.74GB of L2 reads
// = ~121K of the ~300K cycles/CU (L2 per-CU BW ~56B/cyc), invisible in
// FETCH_SIZE (L2 hits). TN=32 -> 1563 blocks -> 0.87GB. B-frags now loaded
// into REGISTERS once per relation and reused across 2 row-tiles (halves
// per-FLOP load exposure too). Gather = v15's proven asm-batched path
// (spans avg 64, cap 128). v16 post-mortem: generic-pointer atomicAdd on LDS
// took a flat/CAS path, 9x regression -- reverted.

#define TN 32

// issue one zext u16 load: dest reg rg <- xq[readlane(eiv, ei) + lane2u]
#define GLD(rg, ei) { u32 voff_ = (u32)__builtin_amdgcn_readlane(eiv, (ei)) + lane2u; \
  asm volatile("global_load_ushort %0, %1, %2" : "=v"(rg) : "v"(voff_), "s"(xq)); }
#define WAITV0 { asm volatile("s_waitcnt vmcnt(0)" ::: "memory"); \
  __builtin_amdgcn_sched_barrier(0); }
// consume edge k of this batch (guarded by runtime wave-uniform cnt)
#define CNS(rg, k) if ((k) < cnt){ int eg_ = sbeg + (k); \
  while (idx < TN && nbv <= eg_) doflush(); \
  float da_, db_; fp8x2_to_f32(rg, da_, db_); a0 += da_; a1 += db_; }

__global__ __launch_bounds__(256, 4) void k_layer(
    const u8*  __restrict__ xq,            // fp8 input (gather + root)
    const u16* __restrict__ WTf,
    const void* __restrict__ bias, const int* __restrict__ off,
    const int* __restrict__ esrc,          // values are src*128 (byte offsets)
    u16* __restrict__ hout,                // bf16 out (iff write_bf)
    u8* __restrict__ hq,                   // fp8 out (iff !write_bf)
    const int* __restrict__ flagp, int write_bf, int relu)
{
  __shared__ __align__(16) u16 Abuf[4][TN*136];  // 34816 B
  __shared__ int soff[RR*(TN+1)];                // 2112 B
  int tid = threadIdx.x;
  int n0 = blockIdx.x * TN;
  int isbf_in = flagp[0];

  int wv = tid >> 6;
  int lane = tid & 63;
  u32 lane2u = (u32)(lane << 1);
  int mrow = lane & 15;
  int quad = lane >> 4;

  // ---- stage off window: soff[r*33+k] = off[r*NN + min(n0+k, NN)] ----
  // clamp handles the tail block (nodes >= NN get empty spans: off at index
  // r*NN+NN equals end-of-relation-r, so span = [end,end]).
  for (int i = tid; i < RR*(TN+1); i += 256){
    int r = i / (TN+1), k = i - r*(TN+1);
    int n = n0 + k; if (n > NN) n = NN;
    soff[i] = off[r*NN + n];
  }
  __syncthreads();

  f32x4 acc[2][2];   // [mt][ct], compile-time indexed everywhere
  { f32x4 z = {0.f,0.f,0.f,0.f};
    acc[0][0]=z; acc[0][1]=z; acc[1][0]=z; acc[1][1]=z; }

  for (int t=0; t<4; ++t){
    int r = t*4 + wv;
    // ---- wave-private gather of 32 nodes, relation r, into Abuf[wv] ----
    {
      int offv = 0;
      if (lane <= TN) offv = soff[r*(TN+1) + lane];
      int wstart = __builtin_amdgcn_readlane(offv, 0);
      int wend   = __builtin_amdgcn_readlane(offv, TN);
      int blen = wend - wstart;

      float a0 = 0.f, a1 = 0.f;
      int idx = 0;
      int cb = wstart;
      int nbv = __builtin_amdgcn_readlane(offv, 1);
      u16* abase = Abuf[wv] + lane*2;

      auto doflush = [&](){
        int cnt_ = nbv - cb;
        float cf = (float)(cnt_ > 0 ? cnt_ : 1);
        float inv = fastrcp(cf);
        *(u32*)(abase + idx*136) = cvt_pk_bf16(a0*inv, a1*inv);
        a0 = 0.f; a1 = 0.f;
        cb = nbv; idx++;
        if (idx < TN) nbv = __builtin_amdgcn_readlane(offv, idx+1);
      };

      if (blen > 0 && blen <= 128){
        // clamped edge-id vectors (ids already src*128); dup of last beyond span
        int c0 = blen - 1;
        int eiv0 = esrc[wstart + (lane < c0 ? lane : c0)];
        int eiv1 = 0;
        if (blen > 64){
          int c1 = blen - 65;
          eiv1 = esrc[wstart + 64 + (lane < c1 ? lane : c1)];
        }

        // up to 32 asm loads (8-granular), one vmcnt(0), consume from regs
        auto batch32 = [&](int eiv, int lb, int sbeg, int cnt)
            __attribute__((always_inline)) {
          u32 r0,r1,r2,r3,r4,r5,r6,r7,r8,r9,r10,r11,r12,r13,r14,r15,
              r16,r17,r18,r19,r20,r21,r22,r23,r24,r25,r26,r27,r28,r29,r30,r31;
          GLD(r0, lb+0) GLD(r1, lb+1) GLD(r2, lb+2) GLD(r3, lb+3)
          GLD(r4, lb+4) GLD(r5, lb+5) GLD(r6, lb+6) GLD(r7, lb+7)
          if (cnt > 8){
            GLD(r8, lb+8)  GLD(r9, lb+9)  GLD(r10, lb+10) GLD(r11, lb+11)
            GLD(r12, lb+12) GLD(r13, lb+13) GLD(r14, lb+14) GLD(r15, lb+15)
          }
          if (cnt > 16){
            GLD(r16, lb+16) GLD(r17, lb+17) GLD(r18, lb+18) GLD(r19, lb+19)
            GLD(r20, lb+20) GLD(r21, lb+21) GLD(r22, lb+22) GLD(r23, lb+23)
          }
          if (cnt > 24){
            GLD(r24, lb+24) GLD(r25, lb+25) GLD(r26, lb+26) GLD(r27, lb+27)
            GLD(r28, lb+28) GLD(r29, lb+29) GLD(r30, lb+30) GLD(r31, lb+31)
          }
          WAITV0
          CNS(r0, 0) CNS(r1, 1) CNS(r2, 2) CNS(r3, 3)
          CNS(r4, 4) CNS(r5, 5) CNS(r6, 6) CNS(r7, 7)
          CNS(r8, 8) CNS(r9, 9) CNS(r10, 10) CNS(r11, 11)
          CNS(r12, 12) CNS(r13, 13) CNS(r14, 14) CNS(r15, 15)
          CNS(r16, 16) CNS(r17, 17) CNS(r18, 18) CNS(r19, 19)
          CNS(r20, 20) CNS(r21, 21) CNS(r22, 22) CNS(r23, 23)
          CNS(r24, 24) CNS(r25, 25) CNS(r26, 26) CNS(r27, 27)
          CNS(r28, 28) CNS(r29, 29) CNS(r30, 30) CNS(r31, 31)
        };

        int cnt0 = blen < 64 ? blen : 64;
        int cA = cnt0 < 32 ? cnt0 : 32;
        batch32(eiv0, 0, wstart, cA);
        if (cnt0 > 32) batch32(eiv0, 32, wstart + 32, cnt0 - 32);
        if (blen > 64){
          int cnt1 = blen - 64;
          int cB = cnt1 < 32 ? cnt1 : 32;
          batch32(eiv1, 0, wstart + 64, cB);
          if (cnt1 > 32) batch32(eiv1, 32, wstart + 96, cnt1 - 32);
        }
      } else if (blen > 0){
        // huge-span fallback (P ~ 0 for this input): serial broadcast loop
        for (int e = wstart; e < wend; ++e){
          int sid = __builtin_amdgcn_readfirstlane(esrc[e]);
          while (idx < TN && nbv <= e) doflush();
          float da, db;
          fp8x2_to_f32((u32)*(const u16*)(xq + (u32)sid + lane2u), da, db);
          a0 += da; a1 += db;
        }
      }
      while (idx < TN) doflush();
    }
    __syncthreads();
    // ---- MFMA: 4 staged relations; wave wv owns cols [32wv, 32wv+32).
    //      B-frags loaded to regs once per relation, reused for 2 row-tiles.
    #pragma unroll
    for (int rloc=0; rloc<4; ++rloc){
      int rr = t*4 + rloc;
      const u16* Bp = WTf + (u32)(((rr*4 + wv)*2)*4*64)*8 + (u32)lane*8;
      short8 bf[2][4];
      #pragma unroll
      for (int ct=0; ct<2; ++ct)
        #pragma unroll
        for (int ks=0; ks<4; ++ks)
          bf[ct][ks] = *(const short8*)(Bp + (u32)(ct*4 + ks)*64*8);
      #pragma unroll
      for (int mt=0; mt<2; ++mt){
        #pragma unroll
        for (int ks=0; ks<4; ++ks){
          short8 af = *(const short8*)(Abuf[rloc] + (mt*16 + mrow)*136 + ks*32 + quad*8);
          #pragma unroll
          for (int ct=0; ct<2; ++ct)
            acc[mt][ct] = __builtin_amdgcn_mfma_f32_16x16x32_bf16(af, bf[ct][ks], acc[mt][ct], 0, 0, 0);
        }
      }
    }
    __syncthreads();   // A tiles free for next round
  }
  // ---- root pass: barrier-free, B-frags once, 2 row-tiles from xq ----
  {
    const u16* Bp = WTf + (u32)(((16*4 + wv)*2)*4*64)*8 + (u32)lane*8;
    short8 bf[2][4];
    #pragma unroll
    for (int ct=0; ct<2; ++ct)
      #pragma unroll
      for (int ks=0; ks<4; ++ks)
        bf[ct][ks] = *(const short8*)(Bp + (u32)(ct*4 + ks)*64*8);
    #pragma unroll
    for (int mt=0; mt<2; ++mt){
      const u8* xrow = xq + (u32)(n0 + mt*16 + mrow)*HD;
      #pragma unroll
      for (int ks=0; ks<4; ++ks){
        u32 lo = *(const u32*)(xrow + ks*32 + quad*8);
        u32 hi = *(const u32*)(xrow + ks*32 + quad*8 + 4);
        float f0,f1,f2,f3,f4,f5,f6,f7;
        fp8x2_to_f32(lo & 0xFFFFu, f0, f1);
        fp8x2_to_f32(lo >> 16,     f2, f3);
        fp8x2_to_f32(hi & 0xFFFFu, f4, f5);
        fp8x2_to_f32(hi >> 16,     f6, f7);
        union { short8 v; u32 w[4]; } u;
        u.w[0] = cvt_pk_bf16(f0,f1); u.w[1] = cvt_pk_bf16(f2,f3);
        u.w[2] = cvt_pk_bf16(f4,f5); u.w[3] = cvt_pk_bf16(f6,f7);
        #pragma unroll
        for (int ct=0; ct<2; ++ct)
          acc[mt][ct] = __builtin_amdgcn_mfma_f32_16x16x32_bf16(u.v, bf[ct][ks], acc[mt][ct], 0, 0, 0);
      }
    }
  }
  // ---- epilogue: node = n0 + mt*16 + quad*4 + rg; col = wv*32 + ct*16 + mrow ----
  #pragma unroll
  for (int mt=0; mt<2; ++mt){
    #pragma unroll
    for (int ct=0; ct<2; ++ct){
      int col = wv*32 + ct*16 + mrow;
      float bv = ldf(bias, col, isbf_in);
      #pragma unroll
      for (int rg=0; rg<4; ++rg){
        int n = n0 + mt*16 + quad*4 + rg;
        if (n < NN){
          float v = acc[mt][ct][rg] + bv;
          if (relu) v = fmaxf(v, 0.f);
          if (!(v == v)) v = 0.f;
          if (write_bf) hout[(u32)(n*HD + col)] = f2bf(v);
          else          hq[(u32)(n*HD + col)] = (u8)(pk_fp8x2(v, 0.f) & 0xFF);
        }
      }
    }
  }
}

// ---------------- global mean pool (bf16 h) + concat + linear head ----------------

__global__ __launch_bounds__(1024) void k_pool_head(
    const u16* __restrict__ h, const int* __restrict__ batch,
    const int* __restrict__ rlab, const void* __restrict__ rel_emb,
    const void* __restrict__ lin_w, const void* __restrict__ lin_b,
    void* __restrict__ out, const int* __restrict__ flagp)
{
  int g = blockIdx.x;
  int isbf = flagp[0];
  __shared__ int bounds[2];
  __shared__ float psum[8][128];
  __shared__ float red[4];
  if (threadIdx.x == 0){
    int lo=0, hi=NN;
    while (lo < hi){ int m=(lo+hi)>>1; if (batch[m] < g) lo=m+1; else hi=m; }
    bounds[0] = lo;
    int lo2=lo, hi2=NN;
    while (lo2 < hi2){ int m=(lo2+hi2)>>1; if (batch[m] < g+1) lo2=m+1; else hi2=m; }
    bounds[1] = lo2;
  }
  __syncthreads();
  int lo = bounds[0], hi = bounds[1];
  int f = threadIdx.x & 127;
  int s = threadIdx.x >> 7;          // 0..7
  float acc = 0.f;
  for (int n = lo + s; n < hi; n += 8) acc += bflo((u32)h[(u32)(n*HD + f)]);
  psum[s][f] = acc;
  __syncthreads();
  if (threadIdx.x < 128){
    int cn = hi - lo;
    float tot = 0.f;
    #pragma unroll
    for (int k=0;k<8;k++) tot += psum[k][f];
    float pooled = tot / (float)(cn > 0 ? cn : 1);
    int rl = rlab[g];
    float re = ldf(rel_emb, rl*HD + f, isbf);
    float v0 = pooled * ldf(lin_w, f*NCLS+0, isbf) + re * ldf(lin_w, (HD+f)*NCLS+0, isbf);
    float v1 = pooled * ldf(lin_w, f*NCLS+1, isbf) + re * ldf(lin_w, (HD+f)*NCLS+1, isbf);
    #pragma unroll
    for (int o=32;o>0;o>>=1){ v0 += __shfl_down(v0,o); v1 += __shfl_down(v1,o); }
    int ln = threadIdx.x & 63, wvv = threadIdx.x >> 6;
    if (ln == 0){ red[wvv*2] = v0; red[wvv*2+1] = v1; }
  }
  __syncthreads();
  if (threadIdx.x == 0){
    float o0 = red[0] + red[2] + ldf(lin_b, 0, isbf);
    float o1 = red[1] + red[3] + ldf(lin_b, 1, isbf);
    if (isbf){
      ((u16*)out)[g*NCLS+0] = f2bf(o0);
      ((u16*)out)[g*NCLS+1] = f2bf(o1);
    } else {
      ((float*)out)[g*NCLS+0] = o0;
      ((float*)out)[g*NCLS+1] = o1;
    }
  }
}

// ---------------- launch ----------------
// ws: flag 256B + off 3.2MB + esrc 6.4MB + WTf3 1.67MB + xq/h1q/h2q 6.4MB x3 +
// h3 12.8MB = 43.3 MB (< 45.37 proven-safe). cnt+bsum alias inside h3.

extern "C" void kernel_launch(void* const* d_in, const int* in_sizes, int n_in,
                              void* d_out, int out_size, void* d_ws, size_t ws_size,
                              hipStream_t stream)
{
  (void)in_sizes; (void)n_in; (void)out_size; (void)ws_size;
  const void* x      = d_in[0];
  const int* eidx    = (const int*)d_in[1];
  const int* etype   = (const int*)d_in[2];
  const int* batch   = (const int*)d_in[3];
  const int* rlab    = (const int*)d_in[4];
  const void* rel_emb = d_in[6];
  const void* basesA[3] = {d_in[7],  d_in[11], d_in[15]};
  const void* compA[3]  = {d_in[8],  d_in[12], d_in[16]};
  const void* rootA[3]  = {d_in[9],  d_in[13], d_in[17]};
  const void* biasA[3]  = {d_in[10], d_in[14], d_in[18]};
  const void* lin_w  = d_in[19];
  const void* lin_b  = d_in[20];

  char* p = (char*)d_ws;
  auto alloc = [&](size_t bytes)->char*{ char* r = p; p += (bytes + 255) & ~(size_t)255; return r; };
  int*   flag   = (int*)  alloc(256);
  int*   off    = (int*)  alloc((size_t)(NRSEG+1)*4);
  int*   esrc   = (int*)  alloc((size_t)(EE+64)*4);
  u16*   WTf    = (u16*)  alloc((size_t)3*17*16384*2);
  u8*    xq     = (u8*)   alloc((size_t)NN*HD);
  u8*    h1q    = (u8*)   alloc((size_t)NN*HD);
  u8*    h2q    = (u8*)   alloc((size_t)NN*HD);
  u16*   h3     = (u16*)  alloc((size_t)NN*HD*2);
  int*   cnt    = (int*)h3;
  int*   bsum   = (int*)((char*)h3 + (size_t)NRSEG*4);

  const int* src_in = eidx;        // edge_index[0]
  const int* dst_in = eidx + EE;   // edge_index[1]

  const int nscan = (NRSEG + SCB - 1) / SCB;   // 782

  k_detect <<<1, 256, 0, stream>>>((const u32*)x, flag);
  k_quant  <<<(NN*HD/4 + 255)/256, 256, 0, stream>>>(x, xq, flag, cnt);
  k_hist   <<<EE/256, 256, 0, stream>>>(dst_in, etype, cnt);
  k_scan1  <<<nscan, SCB, 0, stream>>>(cnt, off, bsum);
  k_scan2  <<<1,    1024, 0, stream>>>(bsum, nscan);
  k_scan3  <<<nscan, SCB, 0, stream>>>(cnt, off, bsum);
  k_scatter<<<EE/256, 256, 0, stream>>>(src_in, dst_in, etype, off, cnt, esrc);

  k_weights3<<<3*1088, 256, 0, stream>>>(basesA[0], compA[0], rootA[0],
                                         basesA[1], compA[1], rootA[1],
                                         basesA[2], compA[2], rootA[2],
                                         WTf, flag);

  const int nblk = (NN + TN - 1) / TN;   // 1563 (tail block handles 16 nodes)
  u16* W0 = WTf;
  u16* W1 = WTf + (size_t)1*17*16384;
  u16* W2 = WTf + (size_t)2*17*16384;
  // layer 1: xq -> h1q (fp8)
  k_layer<<<nblk, 256, 0, stream>>>(xq,  W0, biasA[0], off, esrc, (u16*)0, h1q, flag, 0, 1);
  // layer 2: h1q -> h2q (fp8)
  k_layer<<<nblk, 256, 0, stream>>>(h1q, W1, biasA[1], off, esrc, (u16*)0, h2q, flag, 0, 1);
  // layer 3: h2q -> h3 (bf16, no relu)
  k_layer<<<nblk, 256, 0, stream>>>(h2q, W2, biasA[2], off, esrc, h3, (u8*)0, flag, 1, 0);

  k_pool_head<<<NG, 1024, 0, stream>>>(h3, batch, rlab, rel_emb, lin_w, lin_b,
                                       d_out, flag);
}

// Round 7
// 617.518 us; speedup vs baseline: 5.9705x; 1.0701x over previous
//
#include <hip/hip_runtime.h>

#define NN 50000
#define EE 1600000
#define RR 16
#define NBASE 4
#define FINF 128
#define HD 128
#define NG 64
#define NCLS 2
#define NRSEG (NN*RR)   // 800000

typedef __attribute__((ext_vector_type(8))) short short8;
typedef __attribute__((ext_vector_type(4))) float f32x4;
typedef __attribute__((ext_vector_type(2))) float f32x2;
typedef unsigned short u16;
typedef unsigned int u32;
typedef unsigned long long u64;
typedef unsigned char u8;

__device__ __forceinline__ float bflo(u32 u){ return __builtin_bit_cast(float, u << 16); }
__device__ __forceinline__ float bfhi(u32 u){ return __builtin_bit_cast(float, u & 0xFFFF0000u); }
__device__ __forceinline__ u16 f2bf(float f){
  u32 u = __builtin_bit_cast(u32, f);
  u += 0x7FFFu + ((u >> 16) & 1u);
  return (u16)(u >> 16);
}
// HW packed f32->bf16 (RNE). No builtin on gfx950 (T12 recipe) -> inline asm.
__device__ __forceinline__ u32 cvt_pk_bf16(float a, float b){
  u32 r;
  asm("v_cvt_pk_bf16_f32 %0, %1, %2" : "=v"(r) : "v"(a), "v"(b));
  return r;
}
__device__ __forceinline__ float fastrcp(float x){
#if __has_builtin(__builtin_amdgcn_rcpf)
  return __builtin_amdgcn_rcpf(x);
#else
  return 1.0f / x;
#endif
}
__device__ __forceinline__ float ldf(const void* p, int i, int isbf){
  return isbf ? bflo((u32)((const u16*)p)[i]) : ((const float*)p)[i];
}

// ---------------- fp8 e4m3fn helpers (store paths clamp to +-448) ----------------
__device__ __forceinline__ float fp8_manual(u32 b){
  u32 s = (b>>7)&1, e = (b>>3)&15, m = b&7;
  float v;
  if (e==0) v = (float)m * 0.001953125f;
  else      v = __builtin_bit_cast(float, ((e+120u)<<23) | (m<<20));
  return s ? -v : v;
}
__device__ __forceinline__ u32 f32_to_fp8_manual(float f){
  u32 u = __builtin_bit_cast(u32, f);
  u32 s = u>>31;
  int e = (int)((u>>23)&0xFF);
  u32 m = u & 0x7FFFFF;
  int ee = e - 120;
  if (ee <= 0) return s<<7;
  u32 m3 = m >> 20, rem = m & 0xFFFFF;
  u32 rnd = (rem > 0x80000u) || (rem == 0x80000u && (m3 & 1));
  m3 += rnd;
  if (m3 == 8){ m3 = 0; ee += 1; }
  if (ee >= 16){ ee = 15; m3 = 6; }
  return (s<<7) | ((u32)ee<<3) | m3;
}
__device__ __forceinline__ void fp8x2_to_f32(u32 v, float& a, float& b){
#if __has_builtin(__builtin_amdgcn_cvt_pk_f32_fp8)
  f32x2 r = __builtin_amdgcn_cvt_pk_f32_fp8((int)v, false);
  a = r[0]; b = r[1];
#else
  a = fp8_manual(v & 0xFF); b = fp8_manual((v>>8)&0xFF);
#endif
}
__device__ __forceinline__ u32 pk_fp8x2(float a, float b){
  a = fminf(fmaxf(a, -448.f), 448.f);
  b = fminf(fmaxf(b, -448.f), 448.f);
#if __has_builtin(__builtin_amdgcn_cvt_pk_fp8_f32)
  return (u32)__builtin_amdgcn_cvt_pk_fp8_f32(a, b, 0, false) & 0xFFFF;
#else
  return f32_to_fp8_manual(a) | (f32_to_fp8_manual(b) << 8);
#endif
}

// ---------------- dtype detector ----------------
__global__ void k_detect(const u32* __restrict__ xw, int* __restrict__ flag){
  __shared__ int votes;
  if (threadIdx.x == 0) votes = 0;
  __syncthreads();
  u32 w = xw[threadIdx.x];
  int e = (w >> 7) & 0xFF;
  if (e >= 100 && e <= 129) atomicAdd(&votes, 1);
  __syncthreads();
  if (threadIdx.x == 0) flag[0] = (votes >= 192) ? 1 : 0;
}

// ---------------- quantize x -> fp8 copy (also zeroes cnt[] for k_hist) ----------
__global__ void k_quant(const void* __restrict__ src, u8* __restrict__ dstq,
                        const int* __restrict__ flagp, int* __restrict__ cnt){
  int i = blockIdx.x*256 + threadIdx.x;
  if (i < NRSEG) cnt[i] = 0;                 // replaces hipMemsetAsync
  if (i >= NN*HD/4) return;
  int isbf = flagp[0];
  float v0,v1,v2,v3;
  if (isbf){
    u32 a = ((const u32*)src)[i*2+0], b = ((const u32*)src)[i*2+1];
    v0=bflo(a); v1=bfhi(a); v2=bflo(b); v3=bfhi(b);
  } else {
    float4 f = ((const float4*)src)[i];
    v0=f.x; v1=f.y; v2=f.z; v3=f.w;
  }
  u32 q = pk_fp8x2(v0,v1) | (pk_fp8x2(v2,v3) << 16);
  ((u32*)dstq)[i] = q;
}

// ---------------- CSR build (REL-MAJOR: seg = rel*NN + dst) ----------------

__global__ void k_hist(const int* __restrict__ dst, const int* __restrict__ et,
                       int* __restrict__ cnt){
  int e = blockIdx.x*256 + threadIdx.x;
  if (e < EE) atomicAdd(&cnt[et[e]*NN + dst[e]], 1);
}

#define SCB 1024
__global__ __launch_bounds__(SCB) void k_scan1(const int* __restrict__ cnt,
                                               int* __restrict__ off,
                                               int* __restrict__ bsum){
  __shared__ int sh[SCB];
  int tid = threadIdx.x;
  int i = blockIdx.x*SCB + tid;
  int v = (i < NRSEG) ? cnt[i] : 0;
  sh[tid] = v; __syncthreads();
  for (int d=1; d<SCB; d<<=1){
    int t = (tid >= d) ? sh[tid-d] : 0;
    __syncthreads();
    sh[tid] += t;
    __syncthreads();
  }
  if (i < NRSEG) off[i] = sh[tid] - v;
  if (tid == SCB-1) bsum[blockIdx.x] = sh[SCB-1];
}

__global__ __launch_bounds__(1024) void k_scan2(int* __restrict__ bsum, int nb){
  __shared__ int sh[1024];
  __shared__ int carry;
  int tid = threadIdx.x;
  if (tid == 0) carry = 0;
  __syncthreads();
  for (int base=0; base<nb; base+=1024){
    int i = base + tid;
    int v = (i < nb) ? bsum[i] : 0;
    int orig = v;
    sh[tid] = v; __syncthreads();
    for (int d=1; d<1024; d<<=1){
      int t = (tid >= d) ? sh[tid-d] : 0;
      __syncthreads();
      sh[tid] += t;
      __syncthreads();
    }
    int total = sh[1023];
    int excl = sh[tid] - orig + carry;
    if (i < nb) bsum[i] = excl;
    __syncthreads();
    if (tid == 0) carry += total;
    __syncthreads();
  }
}

__global__ __launch_bounds__(SCB) void k_scan3(const int* __restrict__ cnt,
                                               int* __restrict__ off,
                                               const int* __restrict__ bsum){
  int i = blockIdx.x*SCB + threadIdx.x;
  if (i < NRSEG){
    int o = off[i] + bsum[blockIdx.x];
    off[i] = o;
    if (i == NRSEG-1) off[NRSEG] = o + cnt[i];
  }
}

// NOTE: stores src*128 (pre-shifted byte offset into xq) -- k_layer uses directly
__global__ void k_scatter(const int* __restrict__ src, const int* __restrict__ dst,
                          const int* __restrict__ et, const int* __restrict__ off,
                          int* __restrict__ cnt, int* __restrict__ esrc){
  int e = blockIdx.x*256 + threadIdx.x;
  if (e < EE){
    int seg = et[e]*NN + dst[e];
    int p = atomicSub(&cnt[seg], 1) - 1;
    esrc[off[seg] + p] = src[e] << 7;
  }
}

// ---- weights (bf16, FRAGMENT-SWIZZLED, R11-proven) — all 3 layers fused ----

__global__ void k_weights3(const void* __restrict__ b0, const void* __restrict__ c0,
                           const void* __restrict__ r0,
                           const void* __restrict__ b1, const void* __restrict__ c1,
                           const void* __restrict__ r1,
                           const void* __restrict__ b2, const void* __restrict__ c2,
                           const void* __restrict__ r2,
                           u16* __restrict__ WTf, const int* __restrict__ flagp){
  int gid = blockIdx.x;
  int layer = gid / 1088;
  int blk = gid - layer*1088;
  int idx = blk*256 + threadIdx.x;
  if (idx >= 17*16384) return;
  const void* bases = (layer==0) ? b0 : (layer==1) ? b1 : b2;
  const void* comp  = (layer==0) ? c0 : (layer==1) ? c1 : c2;
  const void* root  = (layer==0) ? r0 : (layer==1) ? r1 : r2;
  u16* W = WTf + (u32)layer * (17*16384);
  int isbf = flagp[0];
  int r = idx >> 14;
  int o = (idx >> 7) & 127;
  int i = idx & 127;
  float v;
  if (r < RR){
    v = 0.f;
    #pragma unroll
    for (int b=0;b<NBASE;b++)
      v += ldf(comp, r*NBASE+b, isbf) * ldf(bases, (b*FINF + i)*HD + o, isbf);
  } else {
    v = ldf(root, i*HD + o, isbf);
  }
  int wv = o >> 5, ct = (o >> 4) & 1, mrow = o & 15;
  int ks = i >> 5, quad = (i >> 3) & 3, j = i & 7;
  int lane = quad*16 + mrow;
  W[(u32)((((r*4+wv)*2+ct)*4+ks)*64 + lane)*8 + j] = f2bf(v);
}

// ---------------- fused aggregate + GEMM layer ----------------
// v18: 8 waves/block (512 thr), TN=32. Diagnosis: all pipes sum to <40us of
// the 129us layer; waves idle ~70% of lifetime at gather latencies + barriers,
// with only 2.65 waves/SIMD resident (Occ 33%, LDS-capped at 50%). Fix the
// untried axis: PARALLELISM. Each relation's span gathered by TWO waves
// (16 nodes each -- split at node boundaries, numerics unchanged); per-wave
// serial gather halves. MFMA: wave w owns 16-col strip (old (wv,ct) =
// (w>>1, w&1)) -> acc 2xf32x4, bf[4]; VGPR drops, launch_bounds(512,8) caps
// at 64 -> with LDS 36.9KB -> 4 blocks/CU = 32 waves/CU = 100% occupancy cap
// (vs 50%). Gather inner machinery = v15's proven asm-batched path.

#define TN 32
#define TNW 16   // nodes per wave (gather granularity)

// issue one zext u16 load: dest reg rg <- xq[readlane(eiv, ei) + lane2u]
#define GLD(rg, ei) { u32 voff_ = (u32)__builtin_amdgcn_readlane(eiv, (ei)) + lane2u; \
  asm volatile("global_load_ushort %0, %1, %2" : "=v"(rg) : "v"(voff_), "s"(xq)); }
#define WAITV0 { asm volatile("s_waitcnt vmcnt(0)" ::: "memory"); \
  __builtin_amdgcn_sched_barrier(0); }
// consume edge k of this batch (guarded by runtime wave-uniform cnt)
#define CNS(rg, k) if ((k) < cnt){ int eg_ = sbeg + (k); \
  while (idx < TNW && nbv <= eg_) doflush(); \
  float da_, db_; fp8x2_to_f32(rg, da_, db_); a0 += da_; a1 += db_; }

__global__ __launch_bounds__(512, 8) void k_layer(
    const u8*  __restrict__ xq,            // fp8 input (gather + root)
    const u16* __restrict__ WTf,
    const void* __restrict__ bias, const int* __restrict__ off,
    const int* __restrict__ esrc,          // values are src*128 (byte offsets)
    u16* __restrict__ hout,                // bf16 out (iff write_bf)
    u8* __restrict__ hq,                   // fp8 out (iff !write_bf)
    const int* __restrict__ flagp, int write_bf, int relu)
{
  __shared__ __align__(16) u16 Abuf[4][TN*136];  // 34816 B
  __shared__ int soff[RR*(TN+1)];                // 2112 B
  int tid = threadIdx.x;
  int n0 = blockIdx.x * TN;
  int isbf_in = flagp[0];

  int w = tid >> 6;        // 0..7
  int lane = tid & 63;
  u32 lane2u = (u32)(lane << 1);
  int mrow = lane & 15;
  int quad = lane >> 4;
  int cwv  = w >> 1;       // 0..3: relation-group (gather) / col-group (MFMA)
  int half = w & 1;        // node-half (gather) / ct (MFMA)

  // ---- stage off window: soff[r*33+k] = off[r*NN + min(n0+k, NN)] ----
  // clamp handles the tail block (nodes >= NN get empty spans).
  for (int i = tid; i < RR*(TN+1); i += 512){
    int r = i / (TN+1), k = i - r*(TN+1);
    int n = n0 + k; if (n > NN) n = NN;
    soff[i] = off[r*NN + n];
  }
  __syncthreads();

  f32x4 acc[2];   // [mt], compile-time indexed everywhere
  { f32x4 z = {0.f,0.f,0.f,0.f}; acc[0] = z; acc[1] = z; }

  for (int t=0; t<4; ++t){
    int r = t*4 + cwv;
    // ---- wave-private gather of 16 nodes [half*16, half*16+16), rel r ----
    {
      int offv = 0;
      if (lane <= TNW) offv = soff[r*(TN+1) + half*TNW + lane];
      int wstart = __builtin_amdgcn_readlane(offv, 0);
      int wend   = __builtin_amdgcn_readlane(offv, TNW);
      int blen = wend - wstart;

      float a0 = 0.f, a1 = 0.f;
      int idx = 0;
      int cb = wstart;
      int nbv = __builtin_amdgcn_readlane(offv, 1);
      u16* abase = Abuf[cwv] + (half*TNW)*136 + lane*2;

      auto doflush = [&](){
        int cnt_ = nbv - cb;
        float cf = (float)(cnt_ > 0 ? cnt_ : 1);
        float inv = fastrcp(cf);
        *(u32*)(abase + idx*136) = cvt_pk_bf16(a0*inv, a1*inv);
        a0 = 0.f; a1 = 0.f;
        cb = nbv; idx++;
        if (idx < TNW) nbv = __builtin_amdgcn_readlane(offv, idx+1);
      };

      if (blen > 0 && blen <= 128){
        // clamped edge-id vectors (ids already src*128); dup of last beyond span
        int c0 = blen - 1;
        int eiv0 = esrc[wstart + (lane < c0 ? lane : c0)];
        int eiv1 = 0;
        if (blen > 64){
          int c1 = blen - 65;
          eiv1 = esrc[wstart + 64 + (lane < c1 ? lane : c1)];
        }

        // up to 32 asm loads (8-granular), one vmcnt(0), consume from regs
        auto batch32 = [&](int eiv, int lb, int sbeg, int cnt)
            __attribute__((always_inline)) {
          u32 r0,r1,r2,r3,r4,r5,r6,r7,r8,r9,r10,r11,r12,r13,r14,r15,
              r16,r17,r18,r19,r20,r21,r22,r23,r24,r25,r26,r27,r28,r29,r30,r31;
          GLD(r0, lb+0) GLD(r1, lb+1) GLD(r2, lb+2) GLD(r3, lb+3)
          GLD(r4, lb+4) GLD(r5, lb+5) GLD(r6, lb+6) GLD(r7, lb+7)
          if (cnt > 8){
            GLD(r8, lb+8)  GLD(r9, lb+9)  GLD(r10, lb+10) GLD(r11, lb+11)
            GLD(r12, lb+12) GLD(r13, lb+13) GLD(r14, lb+14) GLD(r15, lb+15)
          }
          if (cnt > 16){
            GLD(r16, lb+16) GLD(r17, lb+17) GLD(r18, lb+18) GLD(r19, lb+19)
            GLD(r20, lb+20) GLD(r21, lb+21) GLD(r22, lb+22) GLD(r23, lb+23)
          }
          if (cnt > 24){
            GLD(r24, lb+24) GLD(r25, lb+25) GLD(r26, lb+26) GLD(r27, lb+27)
            GLD(r28, lb+28) GLD(r29, lb+29) GLD(r30, lb+30) GLD(r31, lb+31)
          }
          WAITV0
          CNS(r0, 0) CNS(r1, 1) CNS(r2, 2) CNS(r3, 3)
          CNS(r4, 4) CNS(r5, 5) CNS(r6, 6) CNS(r7, 7)
          CNS(r8, 8) CNS(r9, 9) CNS(r10, 10) CNS(r11, 11)
          CNS(r12, 12) CNS(r13, 13) CNS(r14, 14) CNS(r15, 15)
          CNS(r16, 16) CNS(r17, 17) CNS(r18, 18) CNS(r19, 19)
          CNS(r20, 20) CNS(r21, 21) CNS(r22, 22) CNS(r23, 23)
          CNS(r24, 24) CNS(r25, 25) CNS(r26, 26) CNS(r27, 27)
          CNS(r28, 28) CNS(r29, 29) CNS(r30, 30) CNS(r31, 31)
        };

        int cnt0 = blen < 64 ? blen : 64;
        int cA = cnt0 < 32 ? cnt0 : 32;
        batch32(eiv0, 0, wstart, cA);
        if (cnt0 > 32) batch32(eiv0, 32, wstart + 32, cnt0 - 32);
        if (blen > 64){
          int cnt1 = blen - 64;
          int cB = cnt1 < 32 ? cnt1 : 32;
          batch32(eiv1, 0, wstart + 64, cB);
          if (cnt1 > 32) batch32(eiv1, 32, wstart + 96, cnt1 - 32);
        }
      } else if (blen > 0){
        // huge-span fallback (rare): serial broadcast loop
        for (int e = wstart; e < wend; ++e){
          int sid = __builtin_amdgcn_readfirstlane(esrc[e]);
          while (idx < TNW && nbv <= e) doflush();
          float da, db;
          fp8x2_to_f32((u32)*(const u16*)(xq + (u32)sid + lane2u), da, db);
          a0 += da; a1 += db;
        }
      }
      while (idx < TNW) doflush();
    }
    __syncthreads();
    // ---- MFMA: 4 staged relations; wave w owns cols [w*16, w*16+16) ----
    #pragma unroll
    for (int rloc=0; rloc<4; ++rloc){
      int rr = t*4 + rloc;
      const u16* Bp = WTf + (u32)((((rr*4 + cwv)*2 + half)*4)*64)*8 + (u32)lane*8;
      short8 bf[4];
      #pragma unroll
      for (int ks=0; ks<4; ++ks)
        bf[ks] = *(const short8*)(Bp + (u32)ks*64*8);
      #pragma unroll
      for (int mt=0; mt<2; ++mt){
        #pragma unroll
        for (int ks=0; ks<4; ++ks){
          short8 af = *(const short8*)(Abuf[rloc] + (mt*16 + mrow)*136 + ks*32 + quad*8);
          acc[mt] = __builtin_amdgcn_mfma_f32_16x16x32_bf16(af, bf[ks], acc[mt], 0, 0, 0);
        }
      }
    }
    __syncthreads();   // A tiles free for next round
  }
  // ---- root pass: barrier-free, B-frags once, 2 row-tiles from xq ----
  {
    const u16* Bp = WTf + (u32)((((16*4 + cwv)*2 + half)*4)*64)*8 + (u32)lane*8;
    short8 bf[4];
    #pragma unroll
    for (int ks=0; ks<4; ++ks)
      bf[ks] = *(const short8*)(Bp + (u32)ks*64*8);
    #pragma unroll
    for (int mt=0; mt<2; ++mt){
      const u8* xrow = xq + (u32)(n0 + mt*16 + mrow)*HD;
      #pragma unroll
      for (int ks=0; ks<4; ++ks){
        u32 lo = *(const u32*)(xrow + ks*32 + quad*8);
        u32 hi = *(const u32*)(xrow + ks*32 + quad*8 + 4);
        float f0,f1,f2,f3,f4,f5,f6,f7;
        fp8x2_to_f32(lo & 0xFFFFu, f0, f1);
        fp8x2_to_f32(lo >> 16,     f2, f3);
        fp8x2_to_f32(hi & 0xFFFFu, f4, f5);
        fp8x2_to_f32(hi >> 16,     f6, f7);
        union { short8 v; u32 wd[4]; } u;
        u.wd[0] = cvt_pk_bf16(f0,f1); u.wd[1] = cvt_pk_bf16(f2,f3);
        u.wd[2] = cvt_pk_bf16(f4,f5); u.wd[3] = cvt_pk_bf16(f6,f7);
        acc[mt] = __builtin_amdgcn_mfma_f32_16x16x32_bf16(u.v, bf[ks], acc[mt], 0, 0, 0);
      }
    }
  }
  // ---- epilogue: node = n0 + mt*16 + quad*4 + rg; col = w*16 + mrow ----
  {
    int col = cwv*32 + half*16 + mrow;
    float bv = ldf(bias, col, isbf_in);
    #pragma unroll
    for (int mt=0; mt<2; ++mt){
      #pragma unroll
      for (int rg=0; rg<4; ++rg){
        int n = n0 + mt*16 + quad*4 + rg;
        if (n < NN){
          float v = acc[mt][rg] + bv;
          if (relu) v = fmaxf(v, 0.f);
          if (!(v == v)) v = 0.f;
          if (write_bf) hout[(u32)(n*HD + col)] = f2bf(v);
          else          hq[(u32)(n*HD + col)] = (u8)(pk_fp8x2(v, 0.f) & 0xFF);
        }
      }
    }
  }
}

// ---------------- global mean pool (bf16 h) + concat + linear head ----------------

__global__ __launch_bounds__(1024) void k_pool_head(
    const u16* __restrict__ h, const int* __restrict__ batch,
    const int* __restrict__ rlab, const void* __restrict__ rel_emb,
    const void* __restrict__ lin_w, const void* __restrict__ lin_b,
    void* __restrict__ out, const int* __restrict__ flagp)
{
  int g = blockIdx.x;
  int isbf = flagp[0];
  __shared__ int bounds[2];
  __shared__ float psum[8][128];
  __shared__ float red[4];
  if (threadIdx.x == 0){
    int lo=0, hi=NN;
    while (lo < hi){ int m=(lo+hi)>>1; if (batch[m] < g) lo=m+1; else hi=m; }
    bounds[0] = lo;
    int lo2=lo, hi2=NN;
    while (lo2 < hi2){ int m=(lo2+hi2)>>1; if (batch[m] < g+1) lo2=m+1; else hi2=m; }
    bounds[1] = lo2;
  }
  __syncthreads();
  int lo = bounds[0], hi = bounds[1];
  int f = threadIdx.x & 127;
  int s = threadIdx.x >> 7;          // 0..7
  float acc = 0.f;
  for (int n = lo + s; n < hi; n += 8) acc += bflo((u32)h[(u32)(n*HD + f)]);
  psum[s][f] = acc;
  __syncthreads();
  if (threadIdx.x < 128){
    int cn = hi - lo;
    float tot = 0.f;
    #pragma unroll
    for (int k=0;k<8;k++) tot += psum[k][f];
    float pooled = tot / (float)(cn > 0 ? cn : 1);
    int rl = rlab[g];
    float re = ldf(rel_emb, rl*HD + f, isbf);
    float v0 = pooled * ldf(lin_w, f*NCLS+0, isbf) + re * ldf(lin_w, (HD+f)*NCLS+0, isbf);
    float v1 = pooled * ldf(lin_w, f*NCLS+1, isbf) + re * ldf(lin_w, (HD+f)*NCLS+1, isbf);
    #pragma unroll
    for (int o=32;o>0;o>>=1){ v0 += __shfl_down(v0,o); v1 += __shfl_down(v1,o); }
    int ln = threadIdx.x & 63, wvv = threadIdx.x >> 6;
    if (ln == 0){ red[wvv*2] = v0; red[wvv*2+1] = v1; }
  }
  __syncthreads();
  if (threadIdx.x == 0){
    float o0 = red[0] + red[2] + ldf(lin_b, 0, isbf);
    float o1 = red[1] + red[3] + ldf(lin_b, 1, isbf);
    if (isbf){
      ((u16*)out)[g*NCLS+0] = f2bf(o0);
      ((u16*)out)[g*NCLS+1] = f2bf(o1);
    } else {
      ((float*)out)[g*NCLS+0] = o0;
      ((float*)out)[g*NCLS+1] = o1;
    }
  }
}

// ---------------- launch ----------------
// ws: flag 256B + off 3.2MB + esrc 6.4MB + WTf3 1.67MB + xq/h1q/h2q 6.4MB x3 +
// h3 12.8MB = 43.3 MB (< 45.37 proven-safe). cnt+bsum alias inside h3.

extern "C" void kernel_launch(void* const* d_in, const int* in_sizes, int n_in,
                              void* d_out, int out_size, void* d_ws, size_t ws_size,
                              hipStream_t stream)
{
  (void)in_sizes; (void)n_in; (void)out_size; (void)ws_size;
  const void* x      = d_in[0];
  const int* eidx    = (const int*)d_in[1];
  const int* etype   = (const int*)d_in[2];
  const int* batch   = (const int*)d_in[3];
  const int* rlab    = (const int*)d_in[4];
  const void* rel_emb = d_in[6];
  const void* basesA[3] = {d_in[7],  d_in[11], d_in[15]};
  const void* compA[3]  = {d_in[8],  d_in[12], d_in[16]};
  const void* rootA[3]  = {d_in[9],  d_in[13], d_in[17]};
  const void* biasA[3]  = {d_in[10], d_in[14], d_in[18]};
  const void* lin_w  = d_in[19];
  const void* lin_b  = d_in[20];

  char* p = (char*)d_ws;
  auto alloc = [&](size_t bytes)->char*{ char* r = p; p += (bytes + 255) & ~(size_t)255; return r; };
  int*   flag   = (int*)  alloc(256);
  int*   off    = (int*)  alloc((size_t)(NRSEG+1)*4);
  int*   esrc   = (int*)  alloc((size_t)(EE+64)*4);
  u16*   WTf    = (u16*)  alloc((size_t)3*17*16384*2);
  u8*    xq     = (u8*)   alloc((size_t)NN*HD);
  u8*    h1q    = (u8*)   alloc((size_t)NN*HD);
  u8*    h2q    = (u8*)   alloc((size_t)NN*HD);
  u16*   h3     = (u16*)  alloc((size_t)NN*HD*2);
  int*   cnt    = (int*)h3;
  int*   bsum   = (int*)((char*)h3 + (size_t)NRSEG*4);

  const int* src_in = eidx;        // edge_index[0]
  const int* dst_in = eidx + EE;   // edge_index[1]

  const int nscan = (NRSEG + SCB - 1) / SCB;   // 782

  k_detect <<<1, 256, 0, stream>>>((const u32*)x, flag);
  k_quant  <<<(NN*HD/4 + 255)/256, 256, 0, stream>>>(x, xq, flag, cnt);
  k_hist   <<<EE/256, 256, 0, stream>>>(dst_in, etype, cnt);
  k_scan1  <<<nscan, SCB, 0, stream>>>(cnt, off, bsum);
  k_scan2  <<<1,    1024, 0, stream>>>(bsum, nscan);
  k_scan3  <<<nscan, SCB, 0, stream>>>(cnt, off, bsum);
  k_scatter<<<EE/256, 256, 0, stream>>>(src_in, dst_in, etype, off, cnt, esrc);

  k_weights3<<<3*1088, 256, 0, stream>>>(basesA[0], compA[0], rootA[0],
                                         basesA[1], compA[1], rootA[1],
                                         basesA[2], compA[2], rootA[2],
                                         WTf, flag);

  const int nblk = (NN + TN - 1) / TN;   // 1563 (tail block handles 16 nodes)
  u16* W0 = WTf;
  u16* W1 = WTf + (size_t)1*17*16384;
  u16* W2 = WTf + (size_t)2*17*16384;
  // layer 1: xq -> h1q (fp8)
  k_layer<<<nblk, 512, 0, stream>>>(xq,  W0, biasA[0], off, esrc, (u16*)0, h1q, flag, 0, 1);
  // layer 2: h1q -> h2q (fp8)
  k_layer<<<nblk, 512, 0, stream>>>(h1q, W1, biasA[1], off, esrc, (u16*)0, h2q, flag, 0, 1);
  // layer 3: h2q -> h3 (bf16, no relu)
  k_layer<<<nblk, 512, 0, stream>>>(h2q, W2, biasA[2], off, esrc, h3, (u8*)0, flag, 1, 0);

  k_pool_head<<<NG, 1024, 0, stream>>>(h3, batch, rlab, rel_emb, lin_w, lin_b,
                                       d_out, flag);
}

// Round 8
// 613.710 us; speedup vs baseline: 6.0076x; 1.0062x over previous
//
#include <hip/hip_runtime.h>

#define NN 50000
#define EE 1600000
#define RR 16
#define NBASE 4
#define FINF 128
#define HD 128
#define NG 64
#define NCLS 2
#define NRSEG (NN*RR)   // 800000

typedef __attribute__((ext_vector_type(8))) short short8;
typedef __attribute__((ext_vector_type(4))) float f32x4;
typedef __attribute__((ext_vector_type(2))) float f32x2;
typedef unsigned short u16;
typedef unsigned int u32;
typedef unsigned long long u64;
typedef unsigned char u8;

__device__ __forceinline__ float bflo(u32 u){ return __builtin_bit_cast(float, u << 16); }
__device__ __forceinline__ float bfhi(u32 u){ return __builtin_bit_cast(float, u & 0xFFFF0000u); }
__device__ __forceinline__ u16 f2bf(float f){
  u32 u = __builtin_bit_cast(u32, f);
  u += 0x7FFFu + ((u >> 16) & 1u);
  return (u16)(u >> 16);
}
// HW packed f32->bf16 (RNE). No builtin on gfx950 (T12 recipe) -> inline asm.
__device__ __forceinline__ u32 cvt_pk_bf16(float a, float b){
  u32 r;
  asm("v_cvt_pk_bf16_f32 %0, %1, %2" : "=v"(r) : "v"(a), "v"(b));
  return r;
}
__device__ __forceinline__ float fastrcp(float x){
#if __has_builtin(__builtin_amdgcn_rcpf)
  return __builtin_amdgcn_rcpf(x);
#else
  return 1.0f / x;
#endif
}
__device__ __forceinline__ float ldf(const void* p, int i, int isbf){
  return isbf ? bflo((u32)((const u16*)p)[i]) : ((const float*)p)[i];
}

// ---------------- fp8 e4m3fn helpers (store paths clamp to +-448) ----------------
__device__ __forceinline__ float fp8_manual(u32 b){
  u32 s = (b>>7)&1, e = (b>>3)&15, m = b&7;
  float v;
  if (e==0) v = (float)m * 0.001953125f;
  else      v = __builtin_bit_cast(float, ((e+120u)<<23) | (m<<20));
  return s ? -v : v;
}
__device__ __forceinline__ u32 f32_to_fp8_manual(float f){
  u32 u = __builtin_bit_cast(u32, f);
  u32 s = u>>31;
  int e = (int)((u>>23)&0xFF);
  u32 m = u & 0x7FFFFF;
  int ee = e - 120;
  if (ee <= 0) return s<<7;
  u32 m3 = m >> 20, rem = m & 0xFFFFF;
  u32 rnd = (rem > 0x80000u) || (rem == 0x80000u && (m3 & 1));
  m3 += rnd;
  if (m3 == 8){ m3 = 0; ee += 1; }
  if (ee >= 16){ ee = 15; m3 = 6; }
  return (s<<7) | ((u32)ee<<3) | m3;
}
__device__ __forceinline__ void fp8x2_to_f32(u32 v, float& a, float& b){
#if __has_builtin(__builtin_amdgcn_cvt_pk_f32_fp8)
  f32x2 r = __builtin_amdgcn_cvt_pk_f32_fp8((int)v, false);
  a = r[0]; b = r[1];
#else
  a = fp8_manual(v & 0xFF); b = fp8_manual((v>>8)&0xFF);
#endif
}
__device__ __forceinline__ u32 pk_fp8x2(float a, float b){
  a = fminf(fmaxf(a, -448.f), 448.f);
  b = fminf(fmaxf(b, -448.f), 448.f);
#if __has_builtin(__builtin_amdgcn_cvt_pk_fp8_f32)
  return (u32)__builtin_amdgcn_cvt_pk_fp8_f32(a, b, 0, false) & 0xFFFF;
#else
  return f32_to_fp8_manual(a) | (f32_to_fp8_manual(b) << 8);
#endif
}

// ---------------- dtype detector ----------------
__global__ void k_detect(const u32* __restrict__ xw, int* __restrict__ flag){
  __shared__ int votes;
  if (threadIdx.x == 0) votes = 0;
  __syncthreads();
  u32 w = xw[threadIdx.x];
  int e = (w >> 7) & 0xFF;
  if (e >= 100 && e <= 129) atomicAdd(&votes, 1);
  __syncthreads();
  if (threadIdx.x == 0) flag[0] = (votes >= 192) ? 1 : 0;
}

// ---------------- quantize x -> fp8 copy (also zeroes cnt[] for k_hist) ----------
__global__ void k_quant(const void* __restrict__ src, u8* __restrict__ dstq,
                        const int* __restrict__ flagp, int* __restrict__ cnt){
  int i = blockIdx.x*256 + threadIdx.x;
  if (i < NRSEG) cnt[i] = 0;                 // replaces hipMemsetAsync
  if (i >= NN*HD/4) return;
  int isbf = flagp[0];
  float v0,v1,v2,v3;
  if (isbf){
    u32 a = ((const u32*)src)[i*2+0], b = ((const u32*)src)[i*2+1];
    v0=bflo(a); v1=bfhi(a); v2=bflo(b); v3=bfhi(b);
  } else {
    float4 f = ((const float4*)src)[i];
    v0=f.x; v1=f.y; v2=f.z; v3=f.w;
  }
  u32 q = pk_fp8x2(v0,v1) | (pk_fp8x2(v2,v3) << 16);
  ((u32*)dstq)[i] = q;
}

// ---------------- CSR build (REL-MAJOR: seg = rel*NN + dst) ----------------

__global__ void k_hist(const int* __restrict__ dst, const int* __restrict__ et,
                       int* __restrict__ cnt){
  int e = blockIdx.x*256 + threadIdx.x;
  if (e < EE) atomicAdd(&cnt[et[e]*NN + dst[e]], 1);
}

#define SCB 1024
__global__ __launch_bounds__(SCB) void k_scan1(const int* __restrict__ cnt,
                                               int* __restrict__ off,
                                               int* __restrict__ bsum){
  __shared__ int sh[SCB];
  int tid = threadIdx.x;
  int i = blockIdx.x*SCB + tid;
  int v = (i < NRSEG) ? cnt[i] : 0;
  sh[tid] = v; __syncthreads();
  for (int d=1; d<SCB; d<<=1){
    int t = (tid >= d) ? sh[tid-d] : 0;
    __syncthreads();
    sh[tid] += t;
    __syncthreads();
  }
  if (i < NRSEG) off[i] = sh[tid] - v;
  if (tid == SCB-1) bsum[blockIdx.x] = sh[SCB-1];
}

__global__ __launch_bounds__(1024) void k_scan2(int* __restrict__ bsum, int nb){
  __shared__ int sh[1024];
  __shared__ int carry;
  int tid = threadIdx.x;
  if (tid == 0) carry = 0;
  __syncthreads();
  for (int base=0; base<nb; base+=1024){
    int i = base + tid;
    int v = (i < nb) ? bsum[i] : 0;
    int orig = v;
    sh[tid] = v; __syncthreads();
    for (int d=1; d<1024; d<<=1){
      int t = (tid >= d) ? sh[tid-d] : 0;
      __syncthreads();
      sh[tid] += t;
      __syncthreads();
    }
    int total = sh[1023];
    int excl = sh[tid] - orig + carry;
    if (i < nb) bsum[i] = excl;
    __syncthreads();
    if (tid == 0) carry += total;
    __syncthreads();
  }
}

__global__ __launch_bounds__(SCB) void k_scan3(const int* __restrict__ cnt,
                                               int* __restrict__ off,
                                               const int* __restrict__ bsum){
  int i = blockIdx.x*SCB + threadIdx.x;
  if (i < NRSEG){
    int o = off[i] + bsum[blockIdx.x];
    off[i] = o;
    if (i == NRSEG-1) off[NRSEG] = o + cnt[i];
  }
}

// NOTE: stores src*128 (pre-shifted byte offset into xq) -- k_layer uses directly
__global__ void k_scatter(const int* __restrict__ src, const int* __restrict__ dst,
                          const int* __restrict__ et, const int* __restrict__ off,
                          int* __restrict__ cnt, int* __restrict__ esrc){
  int e = blockIdx.x*256 + threadIdx.x;
  if (e < EE){
    int seg = et[e]*NN + dst[e];
    int p = atomicSub(&cnt[seg], 1) - 1;
    esrc[off[seg] + p] = src[e] << 7;
  }
}

// ---- weights (bf16, FRAGMENT-SWIZZLED, R11-proven) — all 3 layers fused ----

__global__ void k_weights3(const void* __restrict__ b0, const void* __restrict__ c0,
                           const void* __restrict__ r0,
                           const void* __restrict__ b1, const void* __restrict__ c1,
                           const void* __restrict__ r1,
                           const void* __restrict__ b2, const void* __restrict__ c2,
                           const void* __restrict__ r2,
                           u16* __restrict__ WTf, const int* __restrict__ flagp){
  int gid = blockIdx.x;
  int layer = gid / 1088;
  int blk = gid - layer*1088;
  int idx = blk*256 + threadIdx.x;
  if (idx >= 17*16384) return;
  const void* bases = (layer==0) ? b0 : (layer==1) ? b1 : b2;
  const void* comp  = (layer==0) ? c0 : (layer==1) ? c1 : c2;
  const void* root  = (layer==0) ? r0 : (layer==1) ? r1 : r2;
  u16* W = WTf + (u32)layer * (17*16384);
  int isbf = flagp[0];
  int r = idx >> 14;
  int o = (idx >> 7) & 127;
  int i = idx & 127;
  float v;
  if (r < RR){
    v = 0.f;
    #pragma unroll
    for (int b=0;b<NBASE;b++)
      v += ldf(comp, r*NBASE+b, isbf) * ldf(bases, (b*FINF + i)*HD + o, isbf);
  } else {
    v = ldf(root, i*HD + o, isbf);
  }
  int wv = o >> 5, ct = (o >> 4) & 1, mrow = o & 15;
  int ks = i >> 5, quad = (i >> 3) & 3, j = i & 7;
  int lane = quad*16 + mrow;
  W[(u32)((((r*4+wv)*2+ct)*4+ks)*64 + lane)*8 + j] = f2bf(v);
}

// ---------------- fused aggregate + GEMM layer ----------------
// v19: v18 (8 waves, TN=32, Occ 33->61%, dur 129->113) minus the spill.
// v18's launch_bounds(512,8) 64-VGPR cap forced ~28MB/dispatch scratch
// traffic (WRITE_SIZE 6250->34017 KB): batch32's 32 live asm regs + gather +
// MFMA state don't fit 64. Fix: batch16 (16 named asm regs, 8-granular issue
// guards) -> ~40 live VGPRs, fits the cap, no spill, keeps the full
// 4 blocks/CU = 32 waves/CU headroom. Cost: 4 vmcnt(0) per 64-edge section
// (vs 2) -- covered by the TLP that v18 proved works.

#define TN 32
#define TNW 16   // nodes per wave (gather granularity)

// issue one zext u16 load: dest reg rg <- xq[readlane(eiv, ei) + lane2u]
#define GLD(rg, ei) { u32 voff_ = (u32)__builtin_amdgcn_readlane(eiv, (ei)) + lane2u; \
  asm volatile("global_load_ushort %0, %1, %2" : "=v"(rg) : "v"(voff_), "s"(xq)); }
#define WAITV0 { asm volatile("s_waitcnt vmcnt(0)" ::: "memory"); \
  __builtin_amdgcn_sched_barrier(0); }
// consume edge k of this batch (guarded by runtime wave-uniform cnt)
#define CNS(rg, k) if ((k) < cnt){ int eg_ = sbeg + (k); \
  while (idx < TNW && nbv <= eg_) doflush(); \
  float da_, db_; fp8x2_to_f32(rg, da_, db_); a0 += da_; a1 += db_; }

__global__ __launch_bounds__(512, 8) void k_layer(
    const u8*  __restrict__ xq,            // fp8 input (gather + root)
    const u16* __restrict__ WTf,
    const void* __restrict__ bias, const int* __restrict__ off,
    const int* __restrict__ esrc,          // values are src*128 (byte offsets)
    u16* __restrict__ hout,                // bf16 out (iff write_bf)
    u8* __restrict__ hq,                   // fp8 out (iff !write_bf)
    const int* __restrict__ flagp, int write_bf, int relu)
{
  __shared__ __align__(16) u16 Abuf[4][TN*136];  // 34816 B
  __shared__ int soff[RR*(TN+1)];                // 2112 B
  int tid = threadIdx.x;
  int n0 = blockIdx.x * TN;
  int isbf_in = flagp[0];

  int w = tid >> 6;        // 0..7
  int lane = tid & 63;
  u32 lane2u = (u32)(lane << 1);
  int mrow = lane & 15;
  int quad = lane >> 4;
  int cwv  = w >> 1;       // 0..3: relation-group (gather) / col-group (MFMA)
  int half = w & 1;        // node-half (gather) / ct (MFMA)

  // ---- stage off window: soff[r*33+k] = off[r*NN + min(n0+k, NN)] ----
  // clamp handles the tail block (nodes >= NN get empty spans).
  for (int i = tid; i < RR*(TN+1); i += 512){
    int r = i / (TN+1), k = i - r*(TN+1);
    int n = n0 + k; if (n > NN) n = NN;
    soff[i] = off[r*NN + n];
  }
  __syncthreads();

  f32x4 acc[2];   // [mt], compile-time indexed everywhere
  { f32x4 z = {0.f,0.f,0.f,0.f}; acc[0] = z; acc[1] = z; }

  for (int t=0; t<4; ++t){
    int r = t*4 + cwv;
    // ---- wave-private gather of 16 nodes [half*16, half*16+16), rel r ----
    {
      int offv = 0;
      if (lane <= TNW) offv = soff[r*(TN+1) + half*TNW + lane];
      int wstart = __builtin_amdgcn_readlane(offv, 0);
      int wend   = __builtin_amdgcn_readlane(offv, TNW);
      int blen = wend - wstart;

      float a0 = 0.f, a1 = 0.f;
      int idx = 0;
      int cb = wstart;
      int nbv = __builtin_amdgcn_readlane(offv, 1);
      u16* abase = Abuf[cwv] + (half*TNW)*136 + lane*2;

      auto doflush = [&](){
        int cnt_ = nbv - cb;
        float cf = (float)(cnt_ > 0 ? cnt_ : 1);
        float inv = fastrcp(cf);
        *(u32*)(abase + idx*136) = cvt_pk_bf16(a0*inv, a1*inv);
        a0 = 0.f; a1 = 0.f;
        cb = nbv; idx++;
        if (idx < TNW) nbv = __builtin_amdgcn_readlane(offv, idx+1);
      };

      if (blen > 0 && blen <= 128){
        // clamped edge-id vectors (ids already src*128); dup of last beyond span
        int c0 = blen - 1;
        int eiv0 = esrc[wstart + (lane < c0 ? lane : c0)];
        int eiv1 = 0;
        if (blen > 64){
          int c1 = blen - 65;
          eiv1 = esrc[wstart + 64 + (lane < c1 ? lane : c1)];
        }

        // 16 asm loads (8-granular), one vmcnt(0), consume from regs.
        // 16 live asm regs (not 32): fits the (512,8) 64-VGPR cap, no spill.
        auto batch16 = [&](int eiv, int lb, int sbeg, int cnt)
            __attribute__((always_inline)) {
          u32 r0,r1,r2,r3,r4,r5,r6,r7,r8,r9,r10,r11,r12,r13,r14,r15;
          GLD(r0, lb+0) GLD(r1, lb+1) GLD(r2, lb+2) GLD(r3, lb+3)
          GLD(r4, lb+4) GLD(r5, lb+5) GLD(r6, lb+6) GLD(r7, lb+7)
          if (cnt > 8){
            GLD(r8, lb+8)  GLD(r9, lb+9)  GLD(r10, lb+10) GLD(r11, lb+11)
            GLD(r12, lb+12) GLD(r13, lb+13) GLD(r14, lb+14) GLD(r15, lb+15)
          }
          WAITV0
          CNS(r0, 0) CNS(r1, 1) CNS(r2, 2) CNS(r3, 3)
          CNS(r4, 4) CNS(r5, 5) CNS(r6, 6) CNS(r7, 7)
          CNS(r8, 8) CNS(r9, 9) CNS(r10, 10) CNS(r11, 11)
          CNS(r12, 12) CNS(r13, 13) CNS(r14, 14) CNS(r15, 15)
        };

        int cnt0 = blen < 64 ? blen : 64;
        batch16(eiv0, 0, wstart, cnt0 < 16 ? cnt0 : 16);
        if (cnt0 > 16) batch16(eiv0, 16, wstart + 16, (cnt0-16) < 16 ? (cnt0-16) : 16);
        if (cnt0 > 32) batch16(eiv0, 32, wstart + 32, (cnt0-32) < 16 ? (cnt0-32) : 16);
        if (cnt0 > 48) batch16(eiv0, 48, wstart + 48, cnt0 - 48);
        if (blen > 64){
          int cnt1 = blen - 64;
          batch16(eiv1, 0, wstart + 64, cnt1 < 16 ? cnt1 : 16);
          if (cnt1 > 16) batch16(eiv1, 16, wstart + 80, (cnt1-16) < 16 ? (cnt1-16) : 16);
          if (cnt1 > 32) batch16(eiv1, 32, wstart + 96, (cnt1-32) < 16 ? (cnt1-32) : 16);
          if (cnt1 > 48) batch16(eiv1, 48, wstart + 112, cnt1 - 48);
        }
      } else if (blen > 0){
        // huge-span fallback (rare): serial broadcast loop
        for (int e = wstart; e < wend; ++e){
          int sid = __builtin_amdgcn_readfirstlane(esrc[e]);
          while (idx < TNW && nbv <= e) doflush();
          float da, db;
          fp8x2_to_f32((u32)*(const u16*)(xq + (u32)sid + lane2u), da, db);
          a0 += da; a1 += db;
        }
      }
      while (idx < TNW) doflush();
    }
    __syncthreads();
    // ---- MFMA: 4 staged relations; wave w owns cols [w*16, w*16+16) ----
    #pragma unroll
    for (int rloc=0; rloc<4; ++rloc){
      int rr = t*4 + rloc;
      const u16* Bp = WTf + (u32)((((rr*4 + cwv)*2 + half)*4)*64)*8 + (u32)lane*8;
      short8 bf[4];
      #pragma unroll
      for (int ks=0; ks<4; ++ks)
        bf[ks] = *(const short8*)(Bp + (u32)ks*64*8);
      #pragma unroll
      for (int mt=0; mt<2; ++mt){
        #pragma unroll
        for (int ks=0; ks<4; ++ks){
          short8 af = *(const short8*)(Abuf[rloc] + (mt*16 + mrow)*136 + ks*32 + quad*8);
          acc[mt] = __builtin_amdgcn_mfma_f32_16x16x32_bf16(af, bf[ks], acc[mt], 0, 0, 0);
        }
      }
    }
    __syncthreads();   // A tiles free for next round
  }
  // ---- root pass: barrier-free, B-frags once, 2 row-tiles from xq ----
  {
    const u16* Bp = WTf + (u32)((((16*4 + cwv)*2 + half)*4)*64)*8 + (u32)lane*8;
    short8 bf[4];
    #pragma unroll
    for (int ks=0; ks<4; ++ks)
      bf[ks] = *(const short8*)(Bp + (u32)ks*64*8);
    #pragma unroll
    for (int mt=0; mt<2; ++mt){
      const u8* xrow = xq + (u32)(n0 + mt*16 + mrow)*HD;
      #pragma unroll
      for (int ks=0; ks<4; ++ks){
        u32 lo = *(const u32*)(xrow + ks*32 + quad*8);
        u32 hi = *(const u32*)(xrow + ks*32 + quad*8 + 4);
        float f0,f1,f2,f3,f4,f5,f6,f7;
        fp8x2_to_f32(lo & 0xFFFFu, f0, f1);
        fp8x2_to_f32(lo >> 16,     f2, f3);
        fp8x2_to_f32(hi & 0xFFFFu, f4, f5);
        fp8x2_to_f32(hi >> 16,     f6, f7);
        union { short8 v; u32 wd[4]; } u;
        u.wd[0] = cvt_pk_bf16(f0,f1); u.wd[1] = cvt_pk_bf16(f2,f3);
        u.wd[2] = cvt_pk_bf16(f4,f5); u.wd[3] = cvt_pk_bf16(f6,f7);
        acc[mt] = __builtin_amdgcn_mfma_f32_16x16x32_bf16(u.v, bf[ks], acc[mt], 0, 0, 0);
      }
    }
  }
  // ---- epilogue: node = n0 + mt*16 + quad*4 + rg; col = w*16 + mrow ----
  {
    int col = cwv*32 + half*16 + mrow;
    float bv = ldf(bias, col, isbf_in);
    #pragma unroll
    for (int mt=0; mt<2; ++mt){
      #pragma unroll
      for (int rg=0; rg<4; ++rg){
        int n = n0 + mt*16 + quad*4 + rg;
        if (n < NN){
          float v = acc[mt][rg] + bv;
          if (relu) v = fmaxf(v, 0.f);
          if (!(v == v)) v = 0.f;
          if (write_bf) hout[(u32)(n*HD + col)] = f2bf(v);
          else          hq[(u32)(n*HD + col)] = (u8)(pk_fp8x2(v, 0.f) & 0xFF);
        }
      }
    }
  }
}

// ---------------- global mean pool (bf16 h) + concat + linear head ----------------

__global__ __launch_bounds__(1024) void k_pool_head(
    const u16* __restrict__ h, const int* __restrict__ batch,
    const int* __restrict__ rlab, const void* __restrict__ rel_emb,
    const void* __restrict__ lin_w, const void* __restrict__ lin_b,
    void* __restrict__ out, const int* __restrict__ flagp)
{
  int g = blockIdx.x;
  int isbf = flagp[0];
  __shared__ int bounds[2];
  __shared__ float psum[8][128];
  __shared__ float red[4];
  if (threadIdx.x == 0){
    int lo=0, hi=NN;
    while (lo < hi){ int m=(lo+hi)>>1; if (batch[m] < g) lo=m+1; else hi=m; }
    bounds[0] = lo;
    int lo2=lo, hi2=NN;
    while (lo2 < hi2){ int m=(lo2+hi2)>>1; if (batch[m] < g+1) lo2=m+1; else hi2=m; }
    bounds[1] = lo2;
  }
  __syncthreads();
  int lo = bounds[0], hi = bounds[1];
  int f = threadIdx.x & 127;
  int s = threadIdx.x >> 7;          // 0..7
  float acc = 0.f;
  for (int n = lo + s; n < hi; n += 8) acc += bflo((u32)h[(u32)(n*HD + f)]);
  psum[s][f] = acc;
  __syncthreads();
  if (threadIdx.x < 128){
    int cn = hi - lo;
    float tot = 0.f;
    #pragma unroll
    for (int k=0;k<8;k++) tot += psum[k][f];
    float pooled = tot / (float)(cn > 0 ? cn : 1);
    int rl = rlab[g];
    float re = ldf(rel_emb, rl*HD + f, isbf);
    float v0 = pooled * ldf(lin_w, f*NCLS+0, isbf) + re * ldf(lin_w, (HD+f)*NCLS+0, isbf);
    float v1 = pooled * ldf(lin_w, f*NCLS+1, isbf) + re * ldf(lin_w, (HD+f)*NCLS+1, isbf);
    #pragma unroll
    for (int o=32;o>0;o>>=1){ v0 += __shfl_down(v0,o); v1 += __shfl_down(v1,o); }
    int ln = threadIdx.x & 63, wvv = threadIdx.x >> 6;
    if (ln == 0){ red[wvv*2] = v0; red[wvv*2+1] = v1; }
  }
  __syncthreads();
  if (threadIdx.x == 0){
    float o0 = red[0] + red[2] + ldf(lin_b, 0, isbf);
    float o1 = red[1] + red[3] + ldf(lin_b, 1, isbf);
    if (isbf){
      ((u16*)out)[g*NCLS+0] = f2bf(o0);
      ((u16*)out)[g*NCLS+1] = f2bf(o1);
    } else {
      ((float*)out)[g*NCLS+0] = o0;
      ((float*)out)[g*NCLS+1] = o1;
    }
  }
}

// ---------------- launch ----------------
// ws: flag 256B + off 3.2MB + esrc 6.4MB + WTf3 1.67MB + xq/h1q/h2q 6.4MB x3 +
// h3 12.8MB = 43.3 MB (< 45.37 proven-safe). cnt+bsum alias inside h3.

extern "C" void kernel_launch(void* const* d_in, const int* in_sizes, int n_in,
                              void* d_out, int out_size, void* d_ws, size_t ws_size,
                              hipStream_t stream)
{
  (void)in_sizes; (void)n_in; (void)out_size; (void)ws_size;
  const void* x      = d_in[0];
  const int* eidx    = (const int*)d_in[1];
  const int* etype   = (const int*)d_in[2];
  const int* batch   = (const int*)d_in[3];
  const int* rlab    = (const int*)d_in[4];
  const void* rel_emb = d_in[6];
  const void* basesA[3] = {d_in[7],  d_in[11], d_in[15]};
  const void* compA[3]  = {d_in[8],  d_in[12], d_in[16]};
  const void* rootA[3]  = {d_in[9],  d_in[13], d_in[17]};
  const void* biasA[3]  = {d_in[10], d_in[14], d_in[18]};
  const void* lin_w  = d_in[19];
  const void* lin_b  = d_in[20];

  char* p = (char*)d_ws;
  auto alloc = [&](size_t bytes)->char*{ char* r = p; p += (bytes + 255) & ~(size_t)255; return r; };
  int*   flag   = (int*)  alloc(256);
  int*   off    = (int*)  alloc((size_t)(NRSEG+1)*4);
  int*   esrc   = (int*)  alloc((size_t)(EE+64)*4);
  u16*   WTf    = (u16*)  alloc((size_t)3*17*16384*2);
  u8*    xq     = (u8*)   alloc((size_t)NN*HD);
  u8*    h1q    = (u8*)   alloc((size_t)NN*HD);
  u8*    h2q    = (u8*)   alloc((size_t)NN*HD);
  u16*   h3     = (u16*)  alloc((size_t)NN*HD*2);
  int*   cnt    = (int*)h3;
  int*   bsum   = (int*)((char*)h3 + (size_t)NRSEG*4);

  const int* src_in = eidx;        // edge_index[0]
  const int* dst_in = eidx + EE;   // edge_index[1]

  const int nscan = (NRSEG + SCB - 1) / SCB;   // 782

  k_detect <<<1, 256, 0, stream>>>((const u32*)x, flag);
  k_quant  <<<(NN*HD/4 + 255)/256, 256, 0, stream>>>(x, xq, flag, cnt);
  k_hist   <<<EE/256, 256, 0, stream>>>(dst_in, etype, cnt);
  k_scan1  <<<nscan, SCB, 0, stream>>>(cnt, off, bsum);
  k_scan2  <<<1,    1024, 0, stream>>>(bsum, nscan);
  k_scan3  <<<nscan, SCB, 0, stream>>>(cnt, off, bsum);
  k_scatter<<<EE/256, 256, 0, stream>>>(src_in, dst_in, etype, off, cnt, esrc);

  k_weights3<<<3*1088, 256, 0, stream>>>(basesA[0], compA[0], rootA[0],
                                         basesA[1], compA[1], rootA[1],
                                         basesA[2], compA[2], rootA[2],
                                         WTf, flag);

  const int nblk = (NN + TN - 1) / TN;   // 1563 (tail block handles 16 nodes)
  u16* W0 = WTf;
  u16* W1 = WTf + (size_t)1*17*16384;
  u16* W2 = WTf + (size_t)2*17*16384;
  // layer 1: xq -> h1q (fp8)
  k_layer<<<nblk, 512, 0, stream>>>(xq,  W0, biasA[0], off, esrc, (u16*)0, h1q, flag, 0, 1);
  // layer 2: h1q -> h2q (fp8)
  k_layer<<<nblk, 512, 0, stream>>>(h1q, W1, biasA[1], off, esrc, (u16*)0, h2q, flag, 0, 1);
  // layer 3: h2q -> h3 (bf16, no relu)
  k_layer<<<nblk, 512, 0, stream>>>(h2q, W2, biasA[2], off, esrc, h3, (u8*)0, flag, 1, 0);

  k_pool_head<<<NG, 1024, 0, stream>>>(h3, batch, rlab, rel_emb, lin_w, lin_b,
                                       d_out, flag);
}

// Round 9
// 608.100 us; speedup vs baseline: 6.0630x; 1.0092x over previous
//
#include <hip/hip_runtime.h>

#define NN 50000
#define EE 1600000
#define RR 16
#define NBASE 4
#define FINF 128
#define HD 128
#define NG 64
#define NCLS 2
#define NRSEG (NN*RR)   // 800000

typedef __attribute__((ext_vector_type(8))) short short8;
typedef __attribute__((ext_vector_type(4))) float f32x4;
typedef __attribute__((ext_vector_type(2))) float f32x2;
typedef unsigned short u16;
typedef unsigned int u32;
typedef unsigned long long u64;
typedef unsigned char u8;

__device__ __forceinline__ float bflo(u32 u){ return __builtin_bit_cast(float, u << 16); }
__device__ __forceinline__ float bfhi(u32 u){ return __builtin_bit_cast(float, u & 0xFFFF0000u); }
__device__ __forceinline__ u16 f2bf(float f){
  u32 u = __builtin_bit_cast(u32, f);
  u += 0x7FFFu + ((u >> 16) & 1u);
  return (u16)(u >> 16);
}
// HW packed f32->bf16 (RNE). No builtin on gfx950 (T12 recipe) -> inline asm.
__device__ __forceinline__ u32 cvt_pk_bf16(float a, float b){
  u32 r;
  asm("v_cvt_pk_bf16_f32 %0, %1, %2" : "=v"(r) : "v"(a), "v"(b));
  return r;
}
__device__ __forceinline__ float fastrcp(float x){
#if __has_builtin(__builtin_amdgcn_rcpf)
  return __builtin_amdgcn_rcpf(x);
#else
  return 1.0f / x;
#endif
}
__device__ __forceinline__ float ldf(const void* p, int i, int isbf){
  return isbf ? bflo((u32)((const u16*)p)[i]) : ((const float*)p)[i];
}

// ---------------- fp8 e4m3fn helpers (store paths clamp to +-448) ----------------
__device__ __forceinline__ float fp8_manual(u32 b){
  u32 s = (b>>7)&1, e = (b>>3)&15, m = b&7;
  float v;
  if (e==0) v = (float)m * 0.001953125f;
  else      v = __builtin_bit_cast(float, ((e+120u)<<23) | (m<<20));
  return s ? -v : v;
}
__device__ __forceinline__ u32 f32_to_fp8_manual(float f){
  u32 u = __builtin_bit_cast(u32, f);
  u32 s = u>>31;
  int e = (int)((u>>23)&0xFF);
  u32 m = u & 0x7FFFFF;
  int ee = e - 120;
  if (ee <= 0) return s<<7;
  u32 m3 = m >> 20, rem = m & 0xFFFFF;
  u32 rnd = (rem > 0x80000u) || (rem == 0x80000u && (m3 & 1));
  m3 += rnd;
  if (m3 == 8){ m3 = 0; ee += 1; }
  if (ee >= 16){ ee = 15; m3 = 6; }
  return (s<<7) | ((u32)ee<<3) | m3;
}
__device__ __forceinline__ void fp8x2_to_f32(u32 v, float& a, float& b){
#if __has_builtin(__builtin_amdgcn_cvt_pk_f32_fp8)
  f32x2 r = __builtin_amdgcn_cvt_pk_f32_fp8((int)v, false);
  a = r[0]; b = r[1];
#else
  a = fp8_manual(v & 0xFF); b = fp8_manual((v>>8)&0xFF);
#endif
}
__device__ __forceinline__ u32 pk_fp8x2(float a, float b){
  a = fminf(fmaxf(a, -448.f), 448.f);
  b = fminf(fmaxf(b, -448.f), 448.f);
#if __has_builtin(__builtin_amdgcn_cvt_pk_fp8_f32)
  return (u32)__builtin_amdgcn_cvt_pk_fp8_f32(a, b, 0, false) & 0xFFFF;
#else
  return f32_to_fp8_manual(a) | (f32_to_fp8_manual(b) << 8);
#endif
}

// ---------------- quantize x -> fp8 copy (fused per-block dtype detect;
// also zeroes cnt[] for k_hist; block 0 publishes flag for later kernels) ----
__global__ void k_quant(const void* __restrict__ src, u8* __restrict__ dstq,
                        int* __restrict__ flag, int* __restrict__ cnt){
  __shared__ int votes;
  int tid = threadIdx.x;
  if (tid == 0) votes = 0;
  __syncthreads();
  {
    u32 w = ((const u32*)src)[tid & 255];   // same L2-hot 1KB for every block
    int e = (w >> 7) & 0xFF;
    if (e >= 100 && e <= 129) atomicAdd(&votes, 1);
  }
  __syncthreads();
  int isbf = (votes >= 192) ? 1 : 0;
  int i = blockIdx.x*256 + tid;
  if (i == 0) flag[0] = isbf;
  if (i < NRSEG) cnt[i] = 0;                 // replaces hipMemsetAsync
  if (i >= NN*HD/4) return;
  float v0,v1,v2,v3;
  if (isbf){
    u32 a = ((const u32*)src)[i*2+0], b = ((const u32*)src)[i*2+1];
    v0=bflo(a); v1=bfhi(a); v2=bflo(b); v3=bfhi(b);
  } else {
    float4 f = ((const float4*)src)[i];
    v0=f.x; v1=f.y; v2=f.z; v3=f.w;
  }
  u32 q = pk_fp8x2(v0,v1) | (pk_fp8x2(v2,v3) << 16);
  ((u32*)dstq)[i] = q;
}

// ---------------- CSR build (REL-MAJOR: seg = rel*NN + dst) ----------------

__global__ void k_hist(const int* __restrict__ dst, const int* __restrict__ et,
                       int* __restrict__ cnt){
  int e = blockIdx.x*256 + threadIdx.x;
  if (e < EE) atomicAdd(&cnt[et[e]*NN + dst[e]], 1);
}

#define SCB 1024
__global__ __launch_bounds__(SCB) void k_scan1(const int* __restrict__ cnt,
                                               int* __restrict__ off,
                                               int* __restrict__ bsum){
  __shared__ int sh[SCB];
  int tid = threadIdx.x;
  int i = blockIdx.x*SCB + tid;
  int v = (i < NRSEG) ? cnt[i] : 0;
  sh[tid] = v; __syncthreads();
  for (int d=1; d<SCB; d<<=1){
    int t = (tid >= d) ? sh[tid-d] : 0;
    __syncthreads();
    sh[tid] += t;
    __syncthreads();
  }
  if (i < NRSEG) off[i] = sh[tid] - v;
  if (tid == SCB-1) bsum[blockIdx.x] = sh[SCB-1];
}

__global__ __launch_bounds__(1024) void k_scan2(int* __restrict__ bsum, int nb){
  __shared__ int sh[1024];
  __shared__ int carry;
  int tid = threadIdx.x;
  if (tid == 0) carry = 0;
  __syncthreads();
  for (int base=0; base<nb; base+=1024){
    int i = base + tid;
    int v = (i < nb) ? bsum[i] : 0;
    int orig = v;
    sh[tid] = v; __syncthreads();
    for (int d=1; d<1024; d<<=1){
      int t = (tid >= d) ? sh[tid-d] : 0;
      __syncthreads();
      sh[tid] += t;
      __syncthreads();
    }
    int total = sh[1023];
    int excl = sh[tid] - orig + carry;
    if (i < nb) bsum[i] = excl;
    __syncthreads();
    if (tid == 0) carry += total;
    __syncthreads();
  }
}

__global__ __launch_bounds__(SCB) void k_scan3(const int* __restrict__ cnt,
                                               int* __restrict__ off,
                                               const int* __restrict__ bsum){
  int i = blockIdx.x*SCB + threadIdx.x;
  if (i < NRSEG){
    int o = off[i] + bsum[blockIdx.x];
    off[i] = o;
    if (i == NRSEG-1) off[NRSEG] = o + cnt[i];
  }
}

// NOTE: stores src*128 (pre-shifted byte offset into xq) -- k_layer uses directly
__global__ void k_scatter(const int* __restrict__ src, const int* __restrict__ dst,
                          const int* __restrict__ et, const int* __restrict__ off,
                          int* __restrict__ cnt, int* __restrict__ esrc){
  int e = blockIdx.x*256 + threadIdx.x;
  if (e < EE){
    int seg = et[e]*NN + dst[e];
    int p = atomicSub(&cnt[seg], 1) - 1;
    esrc[off[seg] + p] = src[e] << 7;
  }
}

// ---- weights (bf16, FRAGMENT-SWIZZLED, R11-proven) — all 3 layers fused ----

__global__ void k_weights3(const void* __restrict__ b0, const void* __restrict__ c0,
                           const void* __restrict__ r0,
                           const void* __restrict__ b1, const void* __restrict__ c1,
                           const void* __restrict__ r1,
                           const void* __restrict__ b2, const void* __restrict__ c2,
                           const void* __restrict__ r2,
                           u16* __restrict__ WTf, const int* __restrict__ flagp){
  int gid = blockIdx.x;
  int layer = gid / 1088;
  int blk = gid - layer*1088;
  int idx = blk*256 + threadIdx.x;
  if (idx >= 17*16384) return;
  const void* bases = (layer==0) ? b0 : (layer==1) ? b1 : b2;
  const void* comp  = (layer==0) ? c0 : (layer==1) ? c1 : c2;
  const void* root  = (layer==0) ? r0 : (layer==1) ? r1 : r2;
  u16* W = WTf + (u32)layer * (17*16384);
  int isbf = flagp[0];
  int r = idx >> 14;
  int o = (idx >> 7) & 127;
  int i = idx & 127;
  float v;
  if (r < RR){
    v = 0.f;
    #pragma unroll
    for (int b=0;b<NBASE;b++)
      v += ldf(comp, r*NBASE+b, isbf) * ldf(bases, (b*FINF + i)*HD + o, isbf);
  } else {
    v = ldf(root, i*HD + o, isbf);
  }
  int wv = o >> 5, ct = (o >> 4) & 1, mrow = o & 15;
  int ks = i >> 5, quad = (i >> 3) & 3, j = i & 7;
  int lane = quad*16 + mrow;
  W[(u32)((((r*4+wv)*2+ct)*4+ks)*64 + lane)*8 + j] = f2bf(v);
}

// ---------------- fused aggregate + GEMM layer ----------------
// v20: v19 minus the spill. v19's VGPR_Count=32 decodes the spill: gfx950
// unified VGPR/AGPR file splits the (512,8) 64-reg budget ~32+32, and the
// live set (acc 8 AGPR + bf[4] CACHE 16 + batch16 16 + misc ~20) exceeds it.
// bf[4] is the cheapest cut: each bf[ks] is used exactly twice within one ks
// iteration -> ks-OUTER loop makes bf live-range 4 regs (was 16), same number
// of B loads, bitwise-identical accumulation order. Live set ~45-50: fits.
// Also: k_detect fused into k_quant (per-block vote, L2-hot 1KB) -- one fewer
// serial launch.

#define TN 32
#define TNW 16   // nodes per wave (gather granularity)

// issue one zext u16 load: dest reg rg <- xq[readlane(eiv, ei) + lane2u]
#define GLD(rg, ei) { u32 voff_ = (u32)__builtin_amdgcn_readlane(eiv, (ei)) + lane2u; \
  asm volatile("global_load_ushort %0, %1, %2" : "=v"(rg) : "v"(voff_), "s"(xq)); }
#define WAITV0 { asm volatile("s_waitcnt vmcnt(0)" ::: "memory"); \
  __builtin_amdgcn_sched_barrier(0); }
// consume edge k of this batch (guarded by runtime wave-uniform cnt)
#define CNS(rg, k) if ((k) < cnt){ int eg_ = sbeg + (k); \
  while (idx < TNW && nbv <= eg_) doflush(); \
  float da_, db_; fp8x2_to_f32(rg, da_, db_); a0 += da_; a1 += db_; }

__global__ __launch_bounds__(512, 8) void k_layer(
    const u8*  __restrict__ xq,            // fp8 input (gather + root)
    const u16* __restrict__ WTf,
    const void* __restrict__ bias, const int* __restrict__ off,
    const int* __restrict__ esrc,          // values are src*128 (byte offsets)
    u16* __restrict__ hout,                // bf16 out (iff write_bf)
    u8* __restrict__ hq,                   // fp8 out (iff !write_bf)
    const int* __restrict__ flagp, int write_bf, int relu)
{
  __shared__ __align__(16) u16 Abuf[4][TN*136];  // 34816 B
  __shared__ int soff[RR*(TN+1)];                // 2112 B
  int tid = threadIdx.x;
  int n0 = blockIdx.x * TN;
  int isbf_in = flagp[0];

  int w = tid >> 6;        // 0..7
  int lane = tid & 63;
  u32 lane2u = (u32)(lane << 1);
  int mrow = lane & 15;
  int quad = lane >> 4;
  int cwv  = w >> 1;       // 0..3: relation-group (gather) / col-group (MFMA)
  int half = w & 1;        // node-half (gather) / ct (MFMA)

  // ---- stage off window: soff[r*33+k] = off[r*NN + min(n0+k, NN)] ----
  // clamp handles the tail block (nodes >= NN get empty spans).
  for (int i = tid; i < RR*(TN+1); i += 512){
    int r = i / (TN+1), k = i - r*(TN+1);
    int n = n0 + k; if (n > NN) n = NN;
    soff[i] = off[r*NN + n];
  }
  __syncthreads();

  f32x4 acc[2];   // [mt], compile-time indexed everywhere
  { f32x4 z = {0.f,0.f,0.f,0.f}; acc[0] = z; acc[1] = z; }

  for (int t=0; t<4; ++t){
    int r = t*4 + cwv;
    // ---- wave-private gather of 16 nodes [half*16, half*16+16), rel r ----
    {
      int offv = 0;
      if (lane <= TNW) offv = soff[r*(TN+1) + half*TNW + lane];
      int wstart = __builtin_amdgcn_readlane(offv, 0);
      int wend   = __builtin_amdgcn_readlane(offv, TNW);
      int blen = wend - wstart;

      float a0 = 0.f, a1 = 0.f;
      int idx = 0;
      int cb = wstart;
      int nbv = __builtin_amdgcn_readlane(offv, 1);
      u16* abase = Abuf[cwv] + (half*TNW)*136 + lane*2;

      auto doflush = [&](){
        int cnt_ = nbv - cb;
        float cf = (float)(cnt_ > 0 ? cnt_ : 1);
        float inv = fastrcp(cf);
        *(u32*)(abase + idx*136) = cvt_pk_bf16(a0*inv, a1*inv);
        a0 = 0.f; a1 = 0.f;
        cb = nbv; idx++;
        if (idx < TNW) nbv = __builtin_amdgcn_readlane(offv, idx+1);
      };

      if (blen > 0 && blen <= 128){
        // clamped edge-id vectors (ids already src*128); dup of last beyond span
        int c0 = blen - 1;
        int eiv0 = esrc[wstart + (lane < c0 ? lane : c0)];
        int eiv1 = 0;
        if (blen > 64){
          int c1 = blen - 65;
          eiv1 = esrc[wstart + 64 + (lane < c1 ? lane : c1)];
        }

        // 16 asm loads (8-granular), one vmcnt(0), consume from regs.
        auto batch16 = [&](int eiv, int lb, int sbeg, int cnt)
            __attribute__((always_inline)) {
          u32 r0,r1,r2,r3,r4,r5,r6,r7,r8,r9,r10,r11,r12,r13,r14,r15;
          GLD(r0, lb+0) GLD(r1, lb+1) GLD(r2, lb+2) GLD(r3, lb+3)
          GLD(r4, lb+4) GLD(r5, lb+5) GLD(r6, lb+6) GLD(r7, lb+7)
          if (cnt > 8){
            GLD(r8, lb+8)  GLD(r9, lb+9)  GLD(r10, lb+10) GLD(r11, lb+11)
            GLD(r12, lb+12) GLD(r13, lb+13) GLD(r14, lb+14) GLD(r15, lb+15)
          }
          WAITV0
          CNS(r0, 0) CNS(r1, 1) CNS(r2, 2) CNS(r3, 3)
          CNS(r4, 4) CNS(r5, 5) CNS(r6, 6) CNS(r7, 7)
          CNS(r8, 8) CNS(r9, 9) CNS(r10, 10) CNS(r11, 11)
          CNS(r12, 12) CNS(r13, 13) CNS(r14, 14) CNS(r15, 15)
        };

        int cnt0 = blen < 64 ? blen : 64;
        batch16(eiv0, 0, wstart, cnt0 < 16 ? cnt0 : 16);
        if (cnt0 > 16) batch16(eiv0, 16, wstart + 16, (cnt0-16) < 16 ? (cnt0-16) : 16);
        if (cnt0 > 32) batch16(eiv0, 32, wstart + 32, (cnt0-32) < 16 ? (cnt0-32) : 16);
        if (cnt0 > 48) batch16(eiv0, 48, wstart + 48, cnt0 - 48);
        if (blen > 64){
          int cnt1 = blen - 64;
          batch16(eiv1, 0, wstart + 64, cnt1 < 16 ? cnt1 : 16);
          if (cnt1 > 16) batch16(eiv1, 16, wstart + 80, (cnt1-16) < 16 ? (cnt1-16) : 16);
          if (cnt1 > 32) batch16(eiv1, 32, wstart + 96, (cnt1-32) < 16 ? (cnt1-32) : 16);
          if (cnt1 > 48) batch16(eiv1, 48, wstart + 112, cnt1 - 48);
        }
      } else if (blen > 0){
        // huge-span fallback (rare): serial broadcast loop
        for (int e = wstart; e < wend; ++e){
          int sid = __builtin_amdgcn_readfirstlane(esrc[e]);
          while (idx < TNW && nbv <= e) doflush();
          float da, db;
          fp8x2_to_f32((u32)*(const u16*)(xq + (u32)sid + lane2u), da, db);
          a0 += da; a1 += db;
        }
      }
      while (idx < TNW) doflush();
    }
    __syncthreads();
    // ---- MFMA: 4 staged relations; wave w owns cols [w*16, w*16+16).
    //      ks-OUTER: one B-frag live at a time (4 regs, was 16) -- same load
    //      count, same accumulation order (rloc asc, ks asc per acc).
    #pragma unroll
    for (int rloc=0; rloc<4; ++rloc){
      int rr = t*4 + rloc;
      const u16* Bp = WTf + (u32)((((rr*4 + cwv)*2 + half)*4)*64)*8 + (u32)lane*8;
      #pragma unroll
      for (int ks=0; ks<4; ++ks){
        short8 bfk = *(const short8*)(Bp + (u32)ks*64*8);
        #pragma unroll
        for (int mt=0; mt<2; ++mt){
          short8 af = *(const short8*)(Abuf[rloc] + (mt*16 + mrow)*136 + ks*32 + quad*8);
          acc[mt] = __builtin_amdgcn_mfma_f32_16x16x32_bf16(af, bfk, acc[mt], 0, 0, 0);
        }
      }
    }
    __syncthreads();   // A tiles free for next round
  }
  // ---- root pass: barrier-free, ks-outer, 2 row-tiles from xq ----
  {
    const u16* Bp = WTf + (u32)((((16*4 + cwv)*2 + half)*4)*64)*8 + (u32)lane*8;
    #pragma unroll
    for (int ks=0; ks<4; ++ks){
      short8 bfk = *(const short8*)(Bp + (u32)ks*64*8);
      #pragma unroll
      for (int mt=0; mt<2; ++mt){
        const u8* xrow = xq + (u32)(n0 + mt*16 + mrow)*HD;
        u32 lo = *(const u32*)(xrow + ks*32 + quad*8);
        u32 hi = *(const u32*)(xrow + ks*32 + quad*8 + 4);
        float f0,f1,f2,f3,f4,f5,f6,f7;
        fp8x2_to_f32(lo & 0xFFFFu, f0, f1);
        fp8x2_to_f32(lo >> 16,     f2, f3);
        fp8x2_to_f32(hi & 0xFFFFu, f4, f5);
        fp8x2_to_f32(hi >> 16,     f6, f7);
        union { short8 v; u32 wd[4]; } u;
        u.wd[0] = cvt_pk_bf16(f0,f1); u.wd[1] = cvt_pk_bf16(f2,f3);
        u.wd[2] = cvt_pk_bf16(f4,f5); u.wd[3] = cvt_pk_bf16(f6,f7);
        acc[mt] = __builtin_amdgcn_mfma_f32_16x16x32_bf16(u.v, bfk, acc[mt], 0, 0, 0);
      }
    }
  }
  // ---- epilogue: node = n0 + mt*16 + quad*4 + rg; col = w*16 + mrow ----
  {
    int col = cwv*32 + half*16 + mrow;
    float bv = ldf(bias, col, isbf_in);
    #pragma unroll
    for (int mt=0; mt<2; ++mt){
      #pragma unroll
      for (int rg=0; rg<4; ++rg){
        int n = n0 + mt*16 + quad*4 + rg;
        if (n < NN){
          float v = acc[mt][rg] + bv;
          if (relu) v = fmaxf(v, 0.f);
          if (!(v == v)) v = 0.f;
          if (write_bf) hout[(u32)(n*HD + col)] = f2bf(v);
          else          hq[(u32)(n*HD + col)] = (u8)(pk_fp8x2(v, 0.f) & 0xFF);
        }
      }
    }
  }
}

// ---------------- global mean pool (bf16 h) + concat + linear head ----------------

__global__ __launch_bounds__(1024) void k_pool_head(
    const u16* __restrict__ h, const int* __restrict__ batch,
    const int* __restrict__ rlab, const void* __restrict__ rel_emb,
    const void* __restrict__ lin_w, const void* __restrict__ lin_b,
    void* __restrict__ out, const int* __restrict__ flagp)
{
  int g = blockIdx.x;
  int isbf = flagp[0];
  __shared__ int bounds[2];
  __shared__ float psum[8][128];
  __shared__ float red[4];
  if (threadIdx.x == 0){
    int lo=0, hi=NN;
    while (lo < hi){ int m=(lo+hi)>>1; if (batch[m] < g) lo=m+1; else hi=m; }
    bounds[0] = lo;
    int lo2=lo, hi2=NN;
    while (lo2 < hi2){ int m=(lo2+hi2)>>1; if (batch[m] < g+1) lo2=m+1; else hi2=m; }
    bounds[1] = lo2;
  }
  __syncthreads();
  int lo = bounds[0], hi = bounds[1];
  int f = threadIdx.x & 127;
  int s = threadIdx.x >> 7;          // 0..7
  float acc = 0.f;
  for (int n = lo + s; n < hi; n += 8) acc += bflo((u32)h[(u32)(n*HD + f)]);
  psum[s][f] = acc;
  __syncthreads();
  if (threadIdx.x < 128){
    int cn = hi - lo;
    float tot = 0.f;
    #pragma unroll
    for (int k=0;k<8;k++) tot += psum[k][f];
    float pooled = tot / (float)(cn > 0 ? cn : 1);
    int rl = rlab[g];
    float re = ldf(rel_emb, rl*HD + f, isbf);
    float v0 = pooled * ldf(lin_w, f*NCLS+0, isbf) + re * ldf(lin_w, (HD+f)*NCLS+0, isbf);
    float v1 = pooled * ldf(lin_w, f*NCLS+1, isbf) + re * ldf(lin_w, (HD+f)*NCLS+1, isbf);
    #pragma unroll
    for (int o=32;o>0;o>>=1){ v0 += __shfl_down(v0,o); v1 += __shfl_down(v1,o); }
    int ln = threadIdx.x & 63, wvv = threadIdx.x >> 6;
    if (ln == 0){ red[wvv*2] = v0; red[wvv*2+1] = v1; }
  }
  __syncthreads();
  if (threadIdx.x == 0){
    float o0 = red[0] + red[2] + ldf(lin_b, 0, isbf);
    float o1 = red[1] + red[3] + ldf(lin_b, 1, isbf);
    if (isbf){
      ((u16*)out)[g*NCLS+0] = f2bf(o0);
      ((u16*)out)[g*NCLS+1] = f2bf(o1);
    } else {
      ((float*)out)[g*NCLS+0] = o0;
      ((float*)out)[g*NCLS+1] = o1;
    }
  }
}

// ---------------- launch ----------------
// ws: flag 256B + off 3.2MB + esrc 6.4MB + WTf3 1.67MB + xq/h1q/h2q 6.4MB x3 +
// h3 12.8MB = 43.3 MB (< 45.37 proven-safe). cnt+bsum alias inside h3.

extern "C" void kernel_launch(void* const* d_in, const int* in_sizes, int n_in,
                              void* d_out, int out_size, void* d_ws, size_t ws_size,
                              hipStream_t stream)
{
  (void)in_sizes; (void)n_in; (void)out_size; (void)ws_size;
  const void* x      = d_in[0];
  const int* eidx    = (const int*)d_in[1];
  const int* etype   = (const int*)d_in[2];
  const int* batch   = (const int*)d_in[3];
  const int* rlab    = (const int*)d_in[4];
  const void* rel_emb = d_in[6];
  const void* basesA[3] = {d_in[7],  d_in[11], d_in[15]};
  const void* compA[3]  = {d_in[8],  d_in[12], d_in[16]};
  const void* rootA[3]  = {d_in[9],  d_in[13], d_in[17]};
  const void* biasA[3]  = {d_in[10], d_in[14], d_in[18]};
  const void* lin_w  = d_in[19];
  const void* lin_b  = d_in[20];

  char* p = (char*)d_ws;
  auto alloc = [&](size_t bytes)->char*{ char* r = p; p += (bytes + 255) & ~(size_t)255; return r; };
  int*   flag   = (int*)  alloc(256);
  int*   off    = (int*)  alloc((size_t)(NRSEG+1)*4);
  int*   esrc   = (int*)  alloc((size_t)(EE+64)*4);
  u16*   WTf    = (u16*)  alloc((size_t)3*17*16384*2);
  u8*    xq     = (u8*)   alloc((size_t)NN*HD);
  u8*    h1q    = (u8*)   alloc((size_t)NN*HD);
  u8*    h2q    = (u8*)   alloc((size_t)NN*HD);
  u16*   h3     = (u16*)  alloc((size_t)NN*HD*2);
  int*   cnt    = (int*)h3;
  int*   bsum   = (int*)((char*)h3 + (size_t)NRSEG*4);

  const int* src_in = eidx;        // edge_index[0]
  const int* dst_in = eidx + EE;   // edge_index[1]

  const int nscan = (NRSEG + SCB - 1) / SCB;   // 782

  k_quant  <<<(NN*HD/4 + 255)/256, 256, 0, stream>>>(x, xq, flag, cnt);
  k_hist   <<<EE/256, 256, 0, stream>>>(dst_in, etype, cnt);
  k_scan1  <<<nscan, SCB, 0, stream>>>(cnt, off, bsum);
  k_scan2  <<<1,    1024, 0, stream>>>(bsum, nscan);
  k_scan3  <<<nscan, SCB, 0, stream>>>(cnt, off, bsum);
  k_scatter<<<EE/256, 256, 0, stream>>>(src_in, dst_in, etype, off, cnt, esrc);

  k_weights3<<<3*1088, 256, 0, stream>>>(basesA[0], compA[0], rootA[0],
                                         basesA[1], compA[1], rootA[1],
                                         basesA[2], compA[2], rootA[2],
                                         WTf, flag);

  const int nblk = (NN + TN - 1) / TN;   // 1563 (tail block handles 16 nodes)
  u16* W0 = WTf;
  u16* W1 = WTf + (size_t)1*17*16384;
  u16* W2 = WTf + (size_t)2*17*16384;
  // layer 1: xq -> h1q (fp8)
  k_layer<<<nblk, 512, 0, stream>>>(xq,  W0, biasA[0], off, esrc, (u16*)0, h1q, flag, 0, 1);
  // layer 2: h1q -> h2q (fp8)
  k_layer<<<nblk, 512, 0, stream>>>(h1q, W1, biasA[1], off, esrc, (u16*)0, h2q, flag, 0, 1);
  // layer 3: h2q -> h3 (bf16, no relu)
  k_layer<<<nblk, 512, 0, stream>>>(h2q, W2, biasA[2], off, esrc, h3, (u8*)0, flag, 1, 0);

  k_pool_head<<<NG, 1024, 0, stream>>>(h3, batch, rlab, rel_emb, lin_w, lin_b,
                                       d_out, flag);
}

// Round 11
// 601.324 us; speedup vs baseline: 6.1313x; 1.0113x over previous
//
#include <hip/hip_runtime.h>

#define NN 50000
#define EE 1600000
#define RR 16
#define NBASE 4
#define FINF 128
#define HD 128
#define NG 64
#define NCLS 2
#define NRSEG (NN*RR)   // 800000

typedef __attribute__((ext_vector_type(8))) short short8;
typedef __attribute__((ext_vector_type(4))) float f32x4;
typedef __attribute__((ext_vector_type(2))) float f32x2;
typedef unsigned short u16;
typedef unsigned int u32;
typedef unsigned long long u64;
typedef unsigned char u8;

__device__ __forceinline__ float bflo(u32 u){ return __builtin_bit_cast(float, u << 16); }
__device__ __forceinline__ float bfhi(u32 u){ return __builtin_bit_cast(float, u & 0xFFFF0000u); }
__device__ __forceinline__ u16 f2bf(float f){
  u32 u = __builtin_bit_cast(u32, f);
  u += 0x7FFFu + ((u >> 16) & 1u);
  return (u16)(u >> 16);
}
// HW packed f32->bf16 (RNE). No builtin on gfx950 (T12 recipe) -> inline asm.
__device__ __forceinline__ u32 cvt_pk_bf16(float a, float b){
  u32 r;
  asm("v_cvt_pk_bf16_f32 %0, %1, %2" : "=v"(r) : "v"(a), "v"(b));
  return r;
}
__device__ __forceinline__ float fastrcp(float x){
#if __has_builtin(__builtin_amdgcn_rcpf)
  return __builtin_amdgcn_rcpf(x);
#else
  return 1.0f / x;
#endif
}
__device__ __forceinline__ float ldf(const void* p, int i, int isbf){
  return isbf ? bflo((u32)((const u16*)p)[i]) : ((const float*)p)[i];
}

// ---------------- fp8 e4m3fn helpers (store paths clamp to +-448) ----------------
__device__ __forceinline__ float fp8_manual(u32 b){
  u32 s = (b>>7)&1, e = (b>>3)&15, m = b&7;
  float v;
  if (e==0) v = (float)m * 0.001953125f;
  else      v = __builtin_bit_cast(float, ((e+120u)<<23) | (m<<20));
  return s ? -v : v;
}
__device__ __forceinline__ u32 f32_to_fp8_manual(float f){
  u32 u = __builtin_bit_cast(u32, f);
  u32 s = u>>31;
  int e = (int)((u>>23)&0xFF);
  u32 m = u & 0x7FFFFF;
  int ee = e - 120;
  if (ee <= 0) return s<<7;
  u32 m3 = m >> 20, rem = m & 0xFFFFF;
  u32 rnd = (rem > 0x80000u) || (rem == 0x80000u && (m3 & 1));
  m3 += rnd;
  if (m3 == 8){ m3 = 0; ee += 1; }
  if (ee >= 16){ ee = 15; m3 = 6; }
  return (s<<7) | ((u32)ee<<3) | m3;
}
__device__ __forceinline__ void fp8x2_to_f32(u32 v, float& a, float& b){
#if __has_builtin(__builtin_amdgcn_cvt_pk_f32_fp8)
  f32x2 r = __builtin_amdgcn_cvt_pk_f32_fp8((int)v, false);
  a = r[0]; b = r[1];
#else
  a = fp8_manual(v & 0xFF); b = fp8_manual((v>>8)&0xFF);
#endif
}
__device__ __forceinline__ u32 pk_fp8x2(float a, float b){
  a = fminf(fmaxf(a, -448.f), 448.f);
  b = fminf(fmaxf(b, -448.f), 448.f);
#if __has_builtin(__builtin_amdgcn_cvt_pk_fp8_f32)
  return (u32)__builtin_amdgcn_cvt_pk_fp8_f32(a, b, 0, false) & 0xFFFF;
#else
  return f32_to_fp8_manual(a) | (f32_to_fp8_manual(b) << 8);
#endif
}

// ---------------- fused quantize + edge histogram ----------------
// Both are exactly 6250 blocks of 256. Per-block dtype vote reads the same
// L2-hot 1KB. cnt[] pre-zeroed by hipMemsetAsync (baseline-proven pattern).
__global__ void k_quant_hist(const void* __restrict__ src, u8* __restrict__ dstq,
                             int* __restrict__ flag,
                             const int* __restrict__ dst, const int* __restrict__ et,
                             int* __restrict__ cnt){
  __shared__ int votes;
  int tid = threadIdx.x;
  if (tid == 0) votes = 0;
  __syncthreads();
  {
    u32 w = ((const u32*)src)[tid];
    int e = (w >> 7) & 0xFF;
    if (e >= 100 && e <= 129) atomicAdd(&votes, 1);
  }
  __syncthreads();
  int isbf = (votes >= 192) ? 1 : 0;
  int i = blockIdx.x*256 + tid;
  if (i == 0) flag[0] = isbf;
  if (i < NN*HD/4){
    float v0,v1,v2,v3;
    if (isbf){
      u32 a = ((const u32*)src)[i*2+0], b = ((const u32*)src)[i*2+1];
      v0=bflo(a); v1=bfhi(a); v2=bflo(b); v3=bfhi(b);
    } else {
      float4 f = ((const float4*)src)[i];
      v0=f.x; v1=f.y; v2=f.z; v3=f.w;
    }
    u32 q = pk_fp8x2(v0,v1) | (pk_fp8x2(v2,v3) << 16);
    ((u32*)dstq)[i] = q;
  }
  if (i < EE) atomicAdd(&cnt[et[i]*NN + dst[i]], 1);
}

// ---------------- CSR build scan (3-kernel, proven) ----------------

#define SCB 1024
__global__ __launch_bounds__(SCB) void k_scan1(const int* __restrict__ cnt,
                                               int* __restrict__ off,
                                               int* __restrict__ bsum){
  __shared__ int sh[SCB];
  int tid = threadIdx.x;
  int i = blockIdx.x*SCB + tid;
  int v = (i < NRSEG) ? cnt[i] : 0;
  sh[tid] = v; __syncthreads();
  for (int d=1; d<SCB; d<<=1){
    int t = (tid >= d) ? sh[tid-d] : 0;
    __syncthreads();
    sh[tid] += t;
    __syncthreads();
  }
  if (i < NRSEG) off[i] = sh[tid] - v;
  if (tid == SCB-1) bsum[blockIdx.x] = sh[SCB-1];
}

__global__ __launch_bounds__(1024) void k_scan2(int* __restrict__ bsum, int nb){
  __shared__ int sh[1024];
  __shared__ int carry;
  int tid = threadIdx.x;
  if (tid == 0) carry = 0;
  __syncthreads();
  for (int base=0; base<nb; base+=1024){
    int i = base + tid;
    int v = (i < nb) ? bsum[i] : 0;
    int orig = v;
    sh[tid] = v; __syncthreads();
    for (int d=1; d<1024; d<<=1){
      int t = (tid >= d) ? sh[tid-d] : 0;
      __syncthreads();
      sh[tid] += t;
      __syncthreads();
    }
    int total = sh[1023];
    int excl = sh[tid] - orig + carry;
    if (i < nb) bsum[i] = excl;
    __syncthreads();
    if (tid == 0) carry += total;
    __syncthreads();
  }
}

__global__ __launch_bounds__(SCB) void k_scan3(const int* __restrict__ cnt,
                                               int* __restrict__ off,
                                               const int* __restrict__ bsum){
  int i = blockIdx.x*SCB + threadIdx.x;
  if (i < NRSEG){
    int o = off[i] + bsum[blockIdx.x];
    off[i] = o;
    if (i == NRSEG-1) off[NRSEG] = o + cnt[i];
  }
}

// NOTE: stores src*128 (pre-shifted byte offset into xq) -- k_layer uses directly
__global__ void k_scatter(const int* __restrict__ src, const int* __restrict__ dst,
                          const int* __restrict__ et, const int* __restrict__ off,
                          int* __restrict__ cnt, int* __restrict__ esrc){
  int e = blockIdx.x*256 + threadIdx.x;
  if (e < EE){
    int seg = et[e]*NN + dst[e];
    int p = atomicSub(&cnt[seg], 1) - 1;
    esrc[off[seg] + p] = src[e] << 7;
  }
}

// ---- weights (bf16, FRAGMENT-SWIZZLED, R11-proven) — all 3 layers fused ----

__global__ void k_weights3(const void* __restrict__ b0, const void* __restrict__ c0,
                           const void* __restrict__ r0,
                           const void* __restrict__ b1, const void* __restrict__ c1,
                           const void* __restrict__ r1,
                           const void* __restrict__ b2, const void* __restrict__ c2,
                           const void* __restrict__ r2,
                           u16* __restrict__ WTf, const int* __restrict__ flagp){
  int gid = blockIdx.x;
  int layer = gid / 1088;
  int blk = gid - layer*1088;
  int idx = blk*256 + threadIdx.x;
  if (idx >= 17*16384) return;
  const void* bases = (layer==0) ? b0 : (layer==1) ? b1 : b2;
  const void* comp  = (layer==0) ? c0 : (layer==1) ? c1 : c2;
  const void* root  = (layer==0) ? r0 : (layer==1) ? r1 : r2;
  u16* W = WTf + (u32)layer * (17*16384);
  int isbf = flagp[0];
  int r = idx >> 14;
  int o = (idx >> 7) & 127;
  int i = idx & 127;
  float v;
  if (r < RR){
    v = 0.f;
    #pragma unroll
    for (int b=0;b<NBASE;b++)
      v += ldf(comp, r*NBASE+b, isbf) * ldf(bases, (b*FINF + i)*HD + o, isbf);
  } else {
    v = ldf(root, i*HD + o, isbf);
  }
  int wv = o >> 5, ct = (o >> 4) & 1, mrow = o & 15;
  int ks = i >> 5, quad = (i >> 3) & 3, j = i & 7;
  int lane = quad*16 + mrow;
  W[(u32)((((r*4+wv)*2+ct)*4+ks)*64 + lane)*8 + j] = f2bf(v);
}

// ---------------- fused aggregate + GEMM layer ----------------
// v22 = v20 (8 waves, TN=32, ks-outer MFMA, no spill, dur 109us) + setprio
// around MFMA clusters (T5; waves at different phases on a SIMD). The v21
// lookback-scan was the likely container-hang -- reverted to 3-kernel scan.

#define TN 32
#define TNW 16   // nodes per wave (gather granularity)

// issue one zext u16 load: dest reg rg <- xq[readlane(eiv, ei) + lane2u]
#define GLD(rg, ei) { u32 voff_ = (u32)__builtin_amdgcn_readlane(eiv, (ei)) + lane2u; \
  asm volatile("global_load_ushort %0, %1, %2" : "=v"(rg) : "v"(voff_), "s"(xq)); }
#define WAITV0 { asm volatile("s_waitcnt vmcnt(0)" ::: "memory"); \
  __builtin_amdgcn_sched_barrier(0); }
// consume edge k of this batch (guarded by runtime wave-uniform cnt)
#define CNS(rg, k) if ((k) < cnt){ int eg_ = sbeg + (k); \
  while (idx < TNW && nbv <= eg_) doflush(); \
  float da_, db_; fp8x2_to_f32(rg, da_, db_); a0 += da_; a1 += db_; }

__global__ __launch_bounds__(512, 8) void k_layer(
    const u8*  __restrict__ xq,            // fp8 input (gather + root)
    const u16* __restrict__ WTf,
    const void* __restrict__ bias, const int* __restrict__ off,
    const int* __restrict__ esrc,          // values are src*128 (byte offsets)
    u16* __restrict__ hout,                // bf16 out (iff write_bf)
    u8* __restrict__ hq,                   // fp8 out (iff !write_bf)
    const int* __restrict__ flagp, int write_bf, int relu)
{
  __shared__ __align__(16) u16 Abuf[4][TN*136];  // 34816 B
  __shared__ int soff[RR*(TN+1)];                // 2112 B
  int tid = threadIdx.x;
  int n0 = blockIdx.x * TN;
  int isbf_in = flagp[0];

  int w = tid >> 6;        // 0..7
  int lane = tid & 63;
  u32 lane2u = (u32)(lane << 1);
  int mrow = lane & 15;
  int quad = lane >> 4;
  int cwv  = w >> 1;       // 0..3: relation-group (gather) / col-group (MFMA)
  int half = w & 1;        // node-half (gather) / ct (MFMA)

  // ---- stage off window: soff[r*33+k] = off[r*NN + min(n0+k, NN)] ----
  // clamp handles the tail block (nodes >= NN get empty spans).
  for (int i = tid; i < RR*(TN+1); i += 512){
    int r = i / (TN+1), k = i - r*(TN+1);
    int n = n0 + k; if (n > NN) n = NN;
    soff[i] = off[r*NN + n];
  }
  __syncthreads();

  f32x4 acc[2];   // [mt], compile-time indexed everywhere
  { f32x4 z = {0.f,0.f,0.f,0.f}; acc[0] = z; acc[1] = z; }

  for (int t=0; t<4; ++t){
    int r = t*4 + cwv;
    // ---- wave-private gather of 16 nodes [half*16, half*16+16), rel r ----
    {
      int offv = 0;
      if (lane <= TNW) offv = soff[r*(TN+1) + half*TNW + lane];
      int wstart = __builtin_amdgcn_readlane(offv, 0);
      int wend   = __builtin_amdgcn_readlane(offv, TNW);
      int blen = wend - wstart;

      float a0 = 0.f, a1 = 0.f;
      int idx = 0;
      int cb = wstart;
      int nbv = __builtin_amdgcn_readlane(offv, 1);
      u16* abase = Abuf[cwv] + (half*TNW)*136 + lane*2;

      auto doflush = [&](){
        int cnt_ = nbv - cb;
        float cf = (float)(cnt_ > 0 ? cnt_ : 1);
        float inv = fastrcp(cf);
        *(u32*)(abase + idx*136) = cvt_pk_bf16(a0*inv, a1*inv);
        a0 = 0.f; a1 = 0.f;
        cb = nbv; idx++;
        if (idx < TNW) nbv = __builtin_amdgcn_readlane(offv, idx+1);
      };

      if (blen > 0 && blen <= 128){
        // clamped edge-id vectors (ids already src*128); dup of last beyond span
        int c0 = blen - 1;
        int eiv0 = esrc[wstart + (lane < c0 ? lane : c0)];
        int eiv1 = 0;
        if (blen > 64){
          int c1 = blen - 65;
          eiv1 = esrc[wstart + 64 + (lane < c1 ? lane : c1)];
        }

        // 16 asm loads (8-granular), one vmcnt(0), consume from regs.
        auto batch16 = [&](int eiv, int lb, int sbeg, int cnt)
            __attribute__((always_inline)) {
          u32 r0,r1,r2,r3,r4,r5,r6,r7,r8,r9,r10,r11,r12,r13,r14,r15;
          GLD(r0, lb+0) GLD(r1, lb+1) GLD(r2, lb+2) GLD(r3, lb+3)
          GLD(r4, lb+4) GLD(r5, lb+5) GLD(r6, lb+6) GLD(r7, lb+7)
          if (cnt > 8){
            GLD(r8, lb+8)  GLD(r9, lb+9)  GLD(r10, lb+10) GLD(r11, lb+11)
            GLD(r12, lb+12) GLD(r13, lb+13) GLD(r14, lb+14) GLD(r15, lb+15)
          }
          WAITV0
          CNS(r0, 0) CNS(r1, 1) CNS(r2, 2) CNS(r3, 3)
          CNS(r4, 4) CNS(r5, 5) CNS(r6, 6) CNS(r7, 7)
          CNS(r8, 8) CNS(r9, 9) CNS(r10, 10) CNS(r11, 11)
          CNS(r12, 12) CNS(r13, 13) CNS(r14, 14) CNS(r15, 15)
        };

        int cnt0 = blen < 64 ? blen : 64;
        batch16(eiv0, 0, wstart, cnt0 < 16 ? cnt0 : 16);
        if (cnt0 > 16) batch16(eiv0, 16, wstart + 16, (cnt0-16) < 16 ? (cnt0-16) : 16);
        if (cnt0 > 32) batch16(eiv0, 32, wstart + 32, (cnt0-32) < 16 ? (cnt0-32) : 16);
        if (cnt0 > 48) batch16(eiv0, 48, wstart + 48, cnt0 - 48);
        if (blen > 64){
          int cnt1 = blen - 64;
          batch16(eiv1, 0, wstart + 64, cnt1 < 16 ? cnt1 : 16);
          if (cnt1 > 16) batch16(eiv1, 16, wstart + 80, (cnt1-16) < 16 ? (cnt1-16) : 16);
          if (cnt1 > 32) batch16(eiv1, 32, wstart + 96, (cnt1-32) < 16 ? (cnt1-32) : 16);
          if (cnt1 > 48) batch16(eiv1, 48, wstart + 112, cnt1 - 48);
        }
      } else if (blen > 0){
        // huge-span fallback (rare): serial broadcast loop
        for (int e = wstart; e < wend; ++e){
          int sid = __builtin_amdgcn_readfirstlane(esrc[e]);
          while (idx < TNW && nbv <= e) doflush();
          float da, db;
          fp8x2_to_f32((u32)*(const u16*)(xq + (u32)sid + lane2u), da, db);
          a0 += da; a1 += db;
        }
      }
      while (idx < TNW) doflush();
    }
    __syncthreads();
    // ---- MFMA: 4 staged relations; wave w owns cols [w*16, w*16+16).
    //      ks-OUTER: one B-frag live at a time; setprio favors MFMA waves.
    __builtin_amdgcn_s_setprio(1);
    #pragma unroll
    for (int rloc=0; rloc<4; ++rloc){
      int rr = t*4 + rloc;
      const u16* Bp = WTf + (u32)((((rr*4 + cwv)*2 + half)*4)*64)*8 + (u32)lane*8;
      #pragma unroll
      for (int ks=0; ks<4; ++ks){
        short8 bfk = *(const short8*)(Bp + (u32)ks*64*8);
        #pragma unroll
        for (int mt=0; mt<2; ++mt){
          short8 af = *(const short8*)(Abuf[rloc] + (mt*16 + mrow)*136 + ks*32 + quad*8);
          acc[mt] = __builtin_amdgcn_mfma_f32_16x16x32_bf16(af, bfk, acc[mt], 0, 0, 0);
        }
      }
    }
    __builtin_amdgcn_s_setprio(0);
    __syncthreads();   // A tiles free for next round
  }
  // ---- root pass: barrier-free, ks-outer, 2 row-tiles from xq ----
  {
    const u16* Bp = WTf + (u32)((((16*4 + cwv)*2 + half)*4)*64)*8 + (u32)lane*8;
    __builtin_amdgcn_s_setprio(1);
    #pragma unroll
    for (int ks=0; ks<4; ++ks){
      short8 bfk = *(const short8*)(Bp + (u32)ks*64*8);
      #pragma unroll
      for (int mt=0; mt<2; ++mt){
        const u8* xrow = xq + (u32)(n0 + mt*16 + mrow)*HD;
        u32 lo = *(const u32*)(xrow + ks*32 + quad*8);
        u32 hi = *(const u32*)(xrow + ks*32 + quad*8 + 4);
        float f0,f1,f2,f3,f4,f5,f6,f7;
        fp8x2_to_f32(lo & 0xFFFFu, f0, f1);
        fp8x2_to_f32(lo >> 16,     f2, f3);
        fp8x2_to_f32(hi & 0xFFFFu, f4, f5);
        fp8x2_to_f32(hi >> 16,     f6, f7);
        union { short8 v; u32 wd[4]; } u;
        u.wd[0] = cvt_pk_bf16(f0,f1); u.wd[1] = cvt_pk_bf16(f2,f3);
        u.wd[2] = cvt_pk_bf16(f4,f5); u.wd[3] = cvt_pk_bf16(f6,f7);
        acc[mt] = __builtin_amdgcn_mfma_f32_16x16x32_bf16(u.v, bfk, acc[mt], 0, 0, 0);
      }
    }
    __builtin_amdgcn_s_setprio(0);
  }
  // ---- epilogue: node = n0 + mt*16 + quad*4 + rg; col = w*16 + mrow ----
  {
    int col = cwv*32 + half*16 + mrow;
    float bv = ldf(bias, col, isbf_in);
    #pragma unroll
    for (int mt=0; mt<2; ++mt){
      #pragma unroll
      for (int rg=0; rg<4; ++rg){
        int n = n0 + mt*16 + quad*4 + rg;
        if (n < NN){
          float v = acc[mt][rg] + bv;
          if (relu) v = fmaxf(v, 0.f);
          if (!(v == v)) v = 0.f;
          if (write_bf) hout[(u32)(n*HD + col)] = f2bf(v);
          else          hq[(u32)(n*HD + col)] = (u8)(pk_fp8x2(v, 0.f) & 0xFF);
        }
      }
    }
  }
}

// ---------------- global mean pool (bf16 h) + concat + linear head ----------------

__global__ __launch_bounds__(1024) void k_pool_head(
    const u16* __restrict__ h, const int* __restrict__ batch,
    const int* __restrict__ rlab, const void* __restrict__ rel_emb,
    const void* __restrict__ lin_w, const void* __restrict__ lin_b,
    void* __restrict__ out, const int* __restrict__ flagp)
{
  int g = blockIdx.x;
  int isbf = flagp[0];
  __shared__ int bounds[2];
  __shared__ float psum[8][128];
  __shared__ float red[4];
  if (threadIdx.x == 0){
    int lo=0, hi=NN;
    while (lo < hi){ int m=(lo+hi)>>1; if (batch[m] < g) lo=m+1; else hi=m; }
    bounds[0] = lo;
    int lo2=lo, hi2=NN;
    while (lo2 < hi2){ int m=(lo2+hi2)>>1; if (batch[m] < g+1) lo2=m+1; else hi2=m; }
    bounds[1] = lo2;
  }
  __syncthreads();
  int lo = bounds[0], hi = bounds[1];
  int f = threadIdx.x & 127;
  int s = threadIdx.x >> 7;          // 0..7
  float acc = 0.f;
  for (int n = lo + s; n < hi; n += 8) acc += bflo((u32)h[(u32)(n*HD + f)]);
  psum[s][f] = acc;
  __syncthreads();
  if (threadIdx.x < 128){
    int cn = hi - lo;
    float tot = 0.f;
    #pragma unroll
    for (int k=0;k<8;k++) tot += psum[k][f];
    float pooled = tot / (float)(cn > 0 ? cn : 1);
    int rl = rlab[g];
    float re = ldf(rel_emb, rl*HD + f, isbf);
    float v0 = pooled * ldf(lin_w, f*NCLS+0, isbf) + re * ldf(lin_w, (HD+f)*NCLS+0, isbf);
    float v1 = pooled * ldf(lin_w, f*NCLS+1, isbf) + re * ldf(lin_w, (HD+f)*NCLS+1, isbf);
    #pragma unroll
    for (int o=32;o>0;o>>=1){ v0 += __shfl_down(v0,o); v1 += __shfl_down(v1,o); }
    int ln = threadIdx.x & 63, wvv = threadIdx.x >> 6;
    if (ln == 0){ red[wvv*2] = v0; red[wvv*2+1] = v1; }
  }
  __syncthreads();
  if (threadIdx.x == 0){
    float o0 = red[0] + red[2] + ldf(lin_b, 0, isbf);
    float o1 = red[1] + red[3] + ldf(lin_b, 1, isbf);
    if (isbf){
      ((u16*)out)[g*NCLS+0] = f2bf(o0);
      ((u16*)out)[g*NCLS+1] = f2bf(o1);
    } else {
      ((float*)out)[g*NCLS+0] = o0;
      ((float*)out)[g*NCLS+1] = o1;
    }
  }
}

// ---------------- launch ----------------
// ws: flag 256B + off 3.2MB + esrc 6.4MB + WTf3 1.67MB + xq/h1q/h2q 6.4MB x3 +
// h3 12.8MB = 43.3 MB (< 45.37 proven-safe). cnt+bsum alias inside h3
// (cnt zeroed by hipMemsetAsync -- baseline-proven).

extern "C" void kernel_launch(void* const* d_in, const int* in_sizes, int n_in,
                              void* d_out, int out_size, void* d_ws, size_t ws_size,
                              hipStream_t stream)
{
  (void)in_sizes; (void)n_in; (void)out_size; (void)ws_size;
  const void* x      = d_in[0];
  const int* eidx    = (const int*)d_in[1];
  const int* etype   = (const int*)d_in[2];
  const int* batch   = (const int*)d_in[3];
  const int* rlab    = (const int*)d_in[4];
  const void* rel_emb = d_in[6];
  const void* basesA[3] = {d_in[7],  d_in[11], d_in[15]};
  const void* compA[3]  = {d_in[8],  d_in[12], d_in[16]};
  const void* rootA[3]  = {d_in[9],  d_in[13], d_in[17]};
  const void* biasA[3]  = {d_in[10], d_in[14], d_in[18]};
  const void* lin_w  = d_in[19];
  const void* lin_b  = d_in[20];

  char* p = (char*)d_ws;
  auto alloc = [&](size_t bytes)->char*{ char* r = p; p += (bytes + 255) & ~(size_t)255; return r; };
  int*   flag   = (int*)  alloc(256);
  int*   off    = (int*)  alloc((size_t)(NRSEG+1)*4);
  int*   esrc   = (int*)  alloc((size_t)(EE+64)*4);
  u16*   WTf    = (u16*)  alloc((size_t)3*17*16384*2);
  u8*    xq     = (u8*)   alloc((size_t)NN*HD);
  u8*    h1q    = (u8*)   alloc((size_t)NN*HD);
  u8*    h2q    = (u8*)   alloc((size_t)NN*HD);
  u16*   h3     = (u16*)  alloc((size_t)NN*HD*2);
  int*   cnt    = (int*)h3;
  int*   bsum   = (int*)((char*)h3 + (size_t)NRSEG*4);

  const int* src_in = eidx;        // edge_index[0]
  const int* dst_in = eidx + EE;   // edge_index[1]

  const int nscan = (NRSEG + SCB - 1) / SCB;   // 782

  hipMemsetAsync(cnt, 0, (size_t)NRSEG*4, stream);
  k_quant_hist<<<EE/256, 256, 0, stream>>>(x, xq, flag, dst_in, etype, cnt);
  k_scan1  <<<nscan, SCB, 0, stream>>>(cnt, off, bsum);
  k_scan2  <<<1,    1024, 0, stream>>>(bsum, nscan);
  k_scan3  <<<nscan, SCB, 0, stream>>>(cnt, off, bsum);
  k_scatter<<<EE/256, 256, 0, stream>>>(src_in, dst_in, etype, off, cnt, esrc);

  k_weights3<<<3*1088, 256, 0, stream>>>(basesA[0], compA[0], rootA[0],
                                         basesA[1], compA[1], rootA[1],
                                         basesA[2], compA[2], rootA[2],
                                         WTf, flag);

  const int nblk = (NN + TN - 1) / TN;   // 1563 (tail block handles 16 nodes)
  u16* W0 = WTf;
  u16* W1 = WTf + (size_t)1*17*16384;
  u16* W2 = WTf + (size_t)2*17*16384;
  // layer 1: xq -> h1q (fp8)
  k_layer<<<nblk, 512, 0, stream>>>(xq,  W0, biasA[0], off, esrc, (u16*)0, h1q, flag, 0, 1);
  // layer 2: h1q -> h2q (fp8)
  k_layer<<<nblk, 512, 0, stream>>>(h1q, W1, biasA[1], off, esrc, (u16*)0, h2q, flag, 0, 1);
  // layer 3: h2q -> h3 (bf16, no relu)
  k_layer<<<nblk, 512, 0, stream>>>(h2q, W2, biasA[2], off, esrc, h3, (u8*)0, flag, 1, 0);

  k_pool_head<<<NG, 1024, 0, stream>>>(h3, batch, rlab, rel_emb, lin_w, lin_b,
                                       d_out, flag);
}

// Round 14
// 594.332 us; speedup vs baseline: 6.2034x; 1.0118x over previous
//
#include <hip/hip_runtime.h>

#define NN 50000
#define EE 1600000
#define RR 16
#define NBASE 4
#define FINF 128
#define HD 128
#define NG 64
#define NCLS 2
#define NRSEG (NN*RR)   // 800000

typedef __attribute__((ext_vector_type(8))) short short8;
typedef __attribute__((ext_vector_type(4))) float f32x4;
typedef __attribute__((ext_vector_type(2))) float f32x2;
typedef unsigned short u16;
typedef unsigned int u32;
typedef unsigned long long u64;
typedef unsigned char u8;

__device__ __forceinline__ float bflo(u32 u){ return __builtin_bit_cast(float, u << 16); }
__device__ __forceinline__ float bfhi(u32 u){ return __builtin_bit_cast(float, u & 0xFFFF0000u); }
__device__ __forceinline__ u16 f2bf(float f){
  u32 u = __builtin_bit_cast(u32, f);
  u += 0x7FFFu + ((u >> 16) & 1u);
  return (u16)(u >> 16);
}
// HW packed f32->bf16 (RNE). No builtin on gfx950 (T12 recipe) -> inline asm.
__device__ __forceinline__ u32 cvt_pk_bf16(float a, float b){
  u32 r;
  asm("v_cvt_pk_bf16_f32 %0, %1, %2" : "=v"(r) : "v"(a), "v"(b));
  return r;
}
__device__ __forceinline__ float fastrcp(float x){
#if __has_builtin(__builtin_amdgcn_rcpf)
  return __builtin_amdgcn_rcpf(x);
#else
  return 1.0f / x;
#endif
}
__device__ __forceinline__ float ldf(const void* p, int i, int isbf){
  return isbf ? bflo((u32)((const u16*)p)[i]) : ((const float*)p)[i];
}

// ---------------- fp8 e4m3fn helpers (store paths clamp to +-448) ----------------
__device__ __forceinline__ float fp8_manual(u32 b){
  u32 s = (b>>7)&1, e = (b>>3)&15, m = b&7;
  float v;
  if (e==0) v = (float)m * 0.001953125f;
  else      v = __builtin_bit_cast(float, ((e+120u)<<23) | (m<<20));
  return s ? -v : v;
}
__device__ __forceinline__ u32 f32_to_fp8_manual(float f){
  u32 u = __builtin_bit_cast(u32, f);
  u32 s = u>>31;
  int e = (int)((u>>23)&0xFF);
  u32 m = u & 0x7FFFFF;
  int ee = e - 120;
  if (ee <= 0) return s<<7;
  u32 m3 = m >> 20, rem = m & 0xFFFFF;
  u32 rnd = (rem > 0x80000u) || (rem == 0x80000u && (m3 & 1));
  m3 += rnd;
  if (m3 == 8){ m3 = 0; ee += 1; }
  if (ee >= 16){ ee = 15; m3 = 6; }
  return (s<<7) | ((u32)ee<<3) | m3;
}
__device__ __forceinline__ void fp8x2_to_f32(u32 v, float& a, float& b){
#if __has_builtin(__builtin_amdgcn_cvt_pk_f32_fp8)
  f32x2 r = __builtin_amdgcn_cvt_pk_f32_fp8((int)v, false);
  a = r[0]; b = r[1];
#else
  a = fp8_manual(v & 0xFF); b = fp8_manual((v>>8)&0xFF);
#endif
}
__device__ __forceinline__ u32 pk_fp8x2(float a, float b){
  a = fminf(fmaxf(a, -448.f), 448.f);
  b = fminf(fmaxf(b, -448.f), 448.f);
#if __has_builtin(__builtin_amdgcn_cvt_pk_fp8_f32)
  return (u32)__builtin_amdgcn_cvt_pk_fp8_f32(a, b, 0, false) & 0xFFFF;
#else
  return f32_to_fp8_manual(a) | (f32_to_fp8_manual(b) << 8);
#endif
}

// ---------------- fused quantize + edge histogram ----------------
// Both are exactly 6250 blocks of 256. Per-block dtype vote reads the same
// L2-hot 1KB. cnt[] pre-zeroed by hipMemsetAsync (baseline-proven pattern).
__global__ void k_quant_hist(const void* __restrict__ src, u8* __restrict__ dstq,
                             int* __restrict__ flag,
                             const int* __restrict__ dst, const int* __restrict__ et,
                             int* __restrict__ cnt){
  __shared__ int votes;
  int tid = threadIdx.x;
  if (tid == 0) votes = 0;
  __syncthreads();
  {
    u32 w = ((const u32*)src)[tid];
    int e = (w >> 7) & 0xFF;
    if (e >= 100 && e <= 129) atomicAdd(&votes, 1);
  }
  __syncthreads();
  int isbf = (votes >= 192) ? 1 : 0;
  int i = blockIdx.x*256 + tid;
  if (i == 0) flag[0] = isbf;
  if (i < NN*HD/4){
    float v0,v1,v2,v3;
    if (isbf){
      u32 a = ((const u32*)src)[i*2+0], b = ((const u32*)src)[i*2+1];
      v0=bflo(a); v1=bfhi(a); v2=bflo(b); v3=bfhi(b);
    } else {
      float4 f = ((const float4*)src)[i];
      v0=f.x; v1=f.y; v2=f.z; v3=f.w;
    }
    u32 q = pk_fp8x2(v0,v1) | (pk_fp8x2(v2,v3) << 16);
    ((u32*)dstq)[i] = q;
  }
  if (i < EE) atomicAdd(&cnt[et[i]*NN + dst[i]], 1);
}

// ---------------- CSR build scan (scan3 FUSED into consumers) ----------------
// scan1 writes block-local exclusive prefixes; scan2 scans block sums; the
// final offset off[i]+bsum[i>>10] is applied on the fly by k_scatter and
// k_layer's soff staging. bsum is in a DEDICATED allocation (v24 post-mortem:
// bsum aliased inside h3 raced with layer-3's h3 writes -> GPU fault).

#define SCB 1024
__global__ __launch_bounds__(SCB) void k_scan1(const int* __restrict__ cnt,
                                               int* __restrict__ off,
                                               int* __restrict__ bsum){
  __shared__ int sh[SCB];
  int tid = threadIdx.x;
  int i = blockIdx.x*SCB + tid;
  int v = (i < NRSEG) ? cnt[i] : 0;
  sh[tid] = v; __syncthreads();
  for (int d=1; d<SCB; d<<=1){
    int t = (tid >= d) ? sh[tid-d] : 0;
    __syncthreads();
    sh[tid] += t;
    __syncthreads();
  }
  if (i < NRSEG) off[i] = sh[tid] - v;
  if (tid == SCB-1) bsum[blockIdx.x] = sh[SCB-1];
}

__global__ __launch_bounds__(1024) void k_scan2(int* __restrict__ bsum, int nb){
  __shared__ int sh[1024];
  __shared__ int carry;
  int tid = threadIdx.x;
  if (tid == 0) carry = 0;
  __syncthreads();
  for (int base=0; base<nb; base+=1024){
    int i = base + tid;
    int v = (i < nb) ? bsum[i] : 0;
    int orig = v;
    sh[tid] = v; __syncthreads();
    for (int d=1; d<1024; d<<=1){
      int t = (tid >= d) ? sh[tid-d] : 0;
      __syncthreads();
      sh[tid] += t;
      __syncthreads();
    }
    int total = sh[1023];
    int excl = sh[tid] - orig + carry;
    if (i < nb) bsum[i] = excl;
    __syncthreads();
    if (tid == 0) carry += total;
    __syncthreads();
  }
}

// NOTE: stores src*128 (pre-shifted byte offset into xq) -- k_layer uses directly
__global__ void k_scatter(const int* __restrict__ src, const int* __restrict__ dst,
                          const int* __restrict__ et, const int* __restrict__ off,
                          const int* __restrict__ bsum,
                          int* __restrict__ cnt, int* __restrict__ esrc){
  int e = blockIdx.x*256 + threadIdx.x;
  if (e < EE){
    int seg = et[e]*NN + dst[e];
    int p = atomicSub(&cnt[seg], 1) - 1;
    esrc[off[seg] + bsum[seg >> 10] + p] = src[e] << 7;
  }
}

// ---- weights (bf16, FRAGMENT-SWIZZLED, R11-proven) — all 3 layers fused ----

__global__ void k_weights3(const void* __restrict__ b0, const void* __restrict__ c0,
                           const void* __restrict__ r0,
                           const void* __restrict__ b1, const void* __restrict__ c1,
                           const void* __restrict__ r1,
                           const void* __restrict__ b2, const void* __restrict__ c2,
                           const void* __restrict__ r2,
                           u16* __restrict__ WTf, const int* __restrict__ flagp){
  int gid = blockIdx.x;
  int layer = gid / 1088;
  int blk = gid - layer*1088;
  int idx = blk*256 + threadIdx.x;
  if (idx >= 17*16384) return;
  const void* bases = (layer==0) ? b0 : (layer==1) ? b1 : b2;
  const void* comp  = (layer==0) ? c0 : (layer==1) ? c1 : c2;
  const void* root  = (layer==0) ? r0 : (layer==1) ? r1 : r2;
  u16* W = WTf + (u32)layer * (17*16384);
  int isbf = flagp[0];
  int r = idx >> 14;
  int o = (idx >> 7) & 127;
  int i = idx & 127;
  float v;
  if (r < RR){
    v = 0.f;
    #pragma unroll
    for (int b=0;b<NBASE;b++)
      v += ldf(comp, r*NBASE+b, isbf) * ldf(bases, (b*FINF + i)*HD + o, isbf);
  } else {
    v = ldf(root, i*HD + o, isbf);
  }
  int wv = o >> 5, ct = (o >> 4) & 1, mrow = o & 15;
  int ks = i >> 5, quad = (i >> 3) & 3, j = i & 7;
  int lane = quad*16 + mrow;
  W[(u32)((((r*4+wv)*2+ct)*4+ks)*64 + lane)*8 + j] = f2bf(v);
}

// ---------------- fused aggregate + GEMM layer ----------------
// v25 = v24 (v22-proven gather, scan3 fusion, setprio) with the aliasing
// bug fixed: bsum now dedicated (was inside h3 -> layer-3 write race).

#define TN 32
#define TNW 16   // nodes per wave (gather granularity)

// issue one zext u16 load: dest reg rg <- xq[readlane(eiv, ei) + lane2u]
#define GLD(rg, ei) { u32 voff_ = (u32)__builtin_amdgcn_readlane(eiv, (ei)) + lane2u; \
  asm volatile("global_load_ushort %0, %1, %2" : "=v"(rg) : "v"(voff_), "s"(xq)); }
#define WAITV0 { asm volatile("s_waitcnt vmcnt(0)" ::: "memory"); \
  __builtin_amdgcn_sched_barrier(0); }
// consume edge k of this batch (guarded by runtime wave-uniform cnt)
#define CNS(rg, k) if ((k) < cnt){ int eg_ = sbeg + (k); \
  while (idx < TNW && nbv <= eg_) doflush(); \
  float da_, db_; fp8x2_to_f32(rg, da_, db_); a0 += da_; a1 += db_; }

__global__ __launch_bounds__(512, 8) void k_layer(
    const u8*  __restrict__ xq,            // fp8 input (gather + root)
    const u16* __restrict__ WTf,
    const void* __restrict__ bias, const int* __restrict__ off,
    const int* __restrict__ bsum,          // block sums (scan3 fused here)
    const int* __restrict__ esrc,          // values are src*128 (byte offsets)
    u16* __restrict__ hout,                // bf16 out (iff write_bf)
    u8* __restrict__ hq,                   // fp8 out (iff !write_bf)
    const int* __restrict__ flagp, int write_bf, int relu)
{
  __shared__ __align__(16) u16 Abuf[4][TN*136];  // 34816 B
  __shared__ int soff[RR*(TN+1)];                // 2112 B
  int tid = threadIdx.x;
  int n0 = blockIdx.x * TN;
  int isbf_in = flagp[0];

  int w = tid >> 6;        // 0..7
  int lane = tid & 63;
  u32 lane2u = (u32)(lane << 1);
  int mrow = lane & 15;
  int quad = lane >> 4;
  int cwv  = w >> 1;       // 0..3: relation-group (gather) / col-group (MFMA)
  int half = w & 1;        // node-half (gather) / ct (MFMA)

  // ---- stage off window: soff = final offset (off + bsum fused), clamped ----
  for (int i = tid; i < RR*(TN+1); i += 512){
    int r = i / (TN+1), k = i - r*(TN+1);
    int n = n0 + k; if (n > NN) n = NN;
    int gi = r*NN + n;
    soff[i] = (gi >= NRSEG) ? EE : (off[gi] + bsum[gi >> 10]);
  }
  __syncthreads();

  f32x4 acc[2];   // [mt], compile-time indexed everywhere
  { f32x4 z = {0.f,0.f,0.f,0.f}; acc[0] = z; acc[1] = z; }

  for (int t=0; t<4; ++t){
    int r = t*4 + cwv;
    // ---- wave-private gather of 16 nodes [half*16, half*16+16), rel r ----
    {
      int offv = 0;
      if (lane <= TNW) offv = soff[r*(TN+1) + half*TNW + lane];
      int wstart = __builtin_amdgcn_readlane(offv, 0);
      int wend   = __builtin_amdgcn_readlane(offv, TNW);
      int blen = wend - wstart;

      float a0 = 0.f, a1 = 0.f;
      int idx = 0;
      int cb = wstart;
      int nbv = __builtin_amdgcn_readlane(offv, 1);
      u16* abase = Abuf[cwv] + (half*TNW)*136 + lane*2;

      auto doflush = [&](){
        int cnt_ = nbv - cb;
        float cf = (float)(cnt_ > 0 ? cnt_ : 1);
        float inv = fastrcp(cf);
        *(u32*)(abase + idx*136) = cvt_pk_bf16(a0*inv, a1*inv);
        a0 = 0.f; a1 = 0.f;
        cb = nbv; idx++;
        if (idx < TNW) nbv = __builtin_amdgcn_readlane(offv, idx+1);
      };

      if (blen > 0 && blen <= 128){
        // clamped edge-id vectors (ids already src*128); dup of last beyond span
        int c0 = blen - 1;
        int eiv0 = esrc[wstart + (lane < c0 ? lane : c0)];
        int eiv1 = 0;
        if (blen > 64){
          int c1 = blen - 65;
          eiv1 = esrc[wstart + 64 + (lane < c1 ? lane : c1)];
        }

        // 16 asm loads (8-granular), one vmcnt(0), consume from regs (v22-proven)
        auto batch16 = [&](int eiv, int lb, int sbeg, int cnt)
            __attribute__((always_inline)) {
          u32 r0,r1,r2,r3,r4,r5,r6,r7,r8,r9,r10,r11,r12,r13,r14,r15;
          GLD(r0, lb+0) GLD(r1, lb+1) GLD(r2, lb+2) GLD(r3, lb+3)
          GLD(r4, lb+4) GLD(r5, lb+5) GLD(r6, lb+6) GLD(r7, lb+7)
          if (cnt > 8){
            GLD(r8, lb+8)  GLD(r9, lb+9)  GLD(r10, lb+10) GLD(r11, lb+11)
            GLD(r12, lb+12) GLD(r13, lb+13) GLD(r14, lb+14) GLD(r15, lb+15)
          }
          WAITV0
          CNS(r0, 0) CNS(r1, 1) CNS(r2, 2) CNS(r3, 3)
          CNS(r4, 4) CNS(r5, 5) CNS(r6, 6) CNS(r7, 7)
          CNS(r8, 8) CNS(r9, 9) CNS(r10, 10) CNS(r11, 11)
          CNS(r12, 12) CNS(r13, 13) CNS(r14, 14) CNS(r15, 15)
        };

        int cnt0 = blen < 64 ? blen : 64;
        batch16(eiv0, 0, wstart, cnt0 < 16 ? cnt0 : 16);
        if (cnt0 > 16) batch16(eiv0, 16, wstart + 16, (cnt0-16) < 16 ? (cnt0-16) : 16);
        if (cnt0 > 32) batch16(eiv0, 32, wstart + 32, (cnt0-32) < 16 ? (cnt0-32) : 16);
        if (cnt0 > 48) batch16(eiv0, 48, wstart + 48, cnt0 - 48);
        if (blen > 64){
          int cnt1 = blen - 64;
          batch16(eiv1, 0, wstart + 64, cnt1 < 16 ? cnt1 : 16);
          if (cnt1 > 16) batch16(eiv1, 16, wstart + 80, (cnt1-16) < 16 ? (cnt1-16) : 16);
          if (cnt1 > 32) batch16(eiv1, 32, wstart + 96, (cnt1-32) < 16 ? (cnt1-32) : 16);
          if (cnt1 > 48) batch16(eiv1, 48, wstart + 112, cnt1 - 48);
        }
      } else if (blen > 0){
        // huge-span fallback (rare): serial broadcast loop
        for (int e = wstart; e < wend; ++e){
          int sid = __builtin_amdgcn_readfirstlane(esrc[e]);
          while (idx < TNW && nbv <= e) doflush();
          float da, db;
          fp8x2_to_f32((u32)*(const u16*)(xq + (u32)sid + lane2u), da, db);
          a0 += da; a1 += db;
        }
      }
      while (idx < TNW) doflush();
    }
    __syncthreads();
    // ---- MFMA: 4 staged relations; wave w owns cols [w*16, w*16+16).
    //      ks-OUTER: one B-frag live at a time; setprio favors MFMA waves.
    __builtin_amdgcn_s_setprio(1);
    #pragma unroll
    for (int rloc=0; rloc<4; ++rloc){
      int rr = t*4 + rloc;
      const u16* Bp = WTf + (u32)((((rr*4 + cwv)*2 + half)*4)*64)*8 + (u32)lane*8;
      #pragma unroll
      for (int ks=0; ks<4; ++ks){
        short8 bfk = *(const short8*)(Bp + (u32)ks*64*8);
        #pragma unroll
        for (int mt=0; mt<2; ++mt){
          short8 af = *(const short8*)(Abuf[rloc] + (mt*16 + mrow)*136 + ks*32 + quad*8);
          acc[mt] = __builtin_amdgcn_mfma_f32_16x16x32_bf16(af, bfk, acc[mt], 0, 0, 0);
        }
      }
    }
    __builtin_amdgcn_s_setprio(0);
    __syncthreads();   // A tiles free for next round
  }
  // ---- root pass: barrier-free, ks-outer, 2 row-tiles from xq ----
  {
    const u16* Bp = WTf + (u32)((((16*4 + cwv)*2 + half)*4)*64)*8 + (u32)lane*8;
    __builtin_amdgcn_s_setprio(1);
    #pragma unroll
    for (int ks=0; ks<4; ++ks){
      short8 bfk = *(const short8*)(Bp + (u32)ks*64*8);
      #pragma unroll
      for (int mt=0; mt<2; ++mt){
        const u8* xrow = xq + (u32)(n0 + mt*16 + mrow)*HD;
        u32 lo = *(const u32*)(xrow + ks*32 + quad*8);
        u32 hi = *(const u32*)(xrow + ks*32 + quad*8 + 4);
        float f0,f1,f2,f3,f4,f5,f6,f7;
        fp8x2_to_f32(lo & 0xFFFFu, f0, f1);
        fp8x2_to_f32(lo >> 16,     f2, f3);
        fp8x2_to_f32(hi & 0xFFFFu, f4, f5);
        fp8x2_to_f32(hi >> 16,     f6, f7);
        union { short8 v; u32 wd[4]; } u;
        u.wd[0] = cvt_pk_bf16(f0,f1); u.wd[1] = cvt_pk_bf16(f2,f3);
        u.wd[2] = cvt_pk_bf16(f4,f5); u.wd[3] = cvt_pk_bf16(f6,f7);
        acc[mt] = __builtin_amdgcn_mfma_f32_16x16x32_bf16(u.v, bfk, acc[mt], 0, 0, 0);
      }
    }
    __builtin_amdgcn_s_setprio(0);
  }
  // ---- epilogue: node = n0 + mt*16 + quad*4 + rg; col = w*16 + mrow ----
  {
    int col = cwv*32 + half*16 + mrow;
    float bv = ldf(bias, col, isbf_in);
    #pragma unroll
    for (int mt=0; mt<2; ++mt){
      #pragma unroll
      for (int rg=0; rg<4; ++rg){
        int n = n0 + mt*16 + quad*4 + rg;
        if (n < NN){
          float v = acc[mt][rg] + bv;
          if (relu) v = fmaxf(v, 0.f);
          if (!(v == v)) v = 0.f;
          if (write_bf) hout[(u32)(n*HD + col)] = f2bf(v);
          else          hq[(u32)(n*HD + col)] = (u8)(pk_fp8x2(v, 0.f) & 0xFF);
        }
      }
    }
  }
}

// ---------------- global mean pool (bf16 h) + concat + linear head ----------------

__global__ __launch_bounds__(1024) void k_pool_head(
    const u16* __restrict__ h, const int* __restrict__ batch,
    const int* __restrict__ rlab, const void* __restrict__ rel_emb,
    const void* __restrict__ lin_w, const void* __restrict__ lin_b,
    void* __restrict__ out, const int* __restrict__ flagp)
{
  int g = blockIdx.x;
  int isbf = flagp[0];
  __shared__ int bounds[2];
  __shared__ float psum[8][128];
  __shared__ float red[4];
  if (threadIdx.x == 0){
    int lo=0, hi=NN;
    while (lo < hi){ int m=(lo+hi)>>1; if (batch[m] < g) lo=m+1; else hi=m; }
    bounds[0] = lo;
    int lo2=lo, hi2=NN;
    while (lo2 < hi2){ int m=(lo2+hi2)>>1; if (batch[m] < g+1) lo2=m+1; else hi2=m; }
    bounds[1] = lo2;
  }
  __syncthreads();
  int lo = bounds[0], hi = bounds[1];
  int f = threadIdx.x & 127;
  int s = threadIdx.x >> 7;          // 0..7
  float acc = 0.f;
  for (int n = lo + s; n < hi; n += 8) acc += bflo((u32)h[(u32)(n*HD + f)]);
  psum[s][f] = acc;
  __syncthreads();
  if (threadIdx.x < 128){
    int cn = hi - lo;
    float tot = 0.f;
    #pragma unroll
    for (int k=0;k<8;k++) tot += psum[k][f];
    float pooled = tot / (float)(cn > 0 ? cn : 1);
    int rl = rlab[g];
    float re = ldf(rel_emb, rl*HD + f, isbf);
    float v0 = pooled * ldf(lin_w, f*NCLS+0, isbf) + re * ldf(lin_w, (HD+f)*NCLS+0, isbf);
    float v1 = pooled * ldf(lin_w, f*NCLS+1, isbf) + re * ldf(lin_w, (HD+f)*NCLS+1, isbf);
    #pragma unroll
    for (int o=32;o>0;o>>=1){ v0 += __shfl_down(v0,o); v1 += __shfl_down(v1,o); }
    int ln = threadIdx.x & 63, wvv = threadIdx.x >> 6;
    if (ln == 0){ red[wvv*2] = v0; red[wvv*2+1] = v1; }
  }
  __syncthreads();
  if (threadIdx.x == 0){
    float o0 = red[0] + red[2] + ldf(lin_b, 0, isbf);
    float o1 = red[1] + red[3] + ldf(lin_b, 1, isbf);
    if (isbf){
      ((u16*)out)[g*NCLS+0] = f2bf(o0);
      ((u16*)out)[g*NCLS+1] = f2bf(o1);
    } else {
      ((float*)out)[g*NCLS+0] = o0;
      ((float*)out)[g*NCLS+1] = o1;
    }
  }
}

// ---------------- launch ----------------
// ws: flag 256B + off 3.2MB + bsum 4KB (DEDICATED -- v24 aliasing bug) +
// esrc 6.4MB + WTf3 1.67MB + xq/h1q/h2q 6.4MB x3 + h3 12.8MB = 43.3 MB
// (< 45.37 proven-safe). cnt aliases h3 (dead before any h3 write).

extern "C" void kernel_launch(void* const* d_in, const int* in_sizes, int n_in,
                              void* d_out, int out_size, void* d_ws, size_t ws_size,
                              hipStream_t stream)
{
  (void)in_sizes; (void)n_in; (void)out_size; (void)ws_size;
  const void* x      = d_in[0];
  const int* eidx    = (const int*)d_in[1];
  const int* etype   = (const int*)d_in[2];
  const int* batch   = (const int*)d_in[3];
  const int* rlab    = (const int*)d_in[4];
  const void* rel_emb = d_in[6];
  const void* basesA[3] = {d_in[7],  d_in[11], d_in[15]};
  const void* compA[3]  = {d_in[8],  d_in[12], d_in[16]};
  const void* rootA[3]  = {d_in[9],  d_in[13], d_in[17]};
  const void* biasA[3]  = {d_in[10], d_in[14], d_in[18]};
  const void* lin_w  = d_in[19];
  const void* lin_b  = d_in[20];

  char* p = (char*)d_ws;
  auto alloc = [&](size_t bytes)->char*{ char* r = p; p += (bytes + 255) & ~(size_t)255; return r; };
  int*   flag   = (int*)  alloc(256);
  int*   off    = (int*)  alloc((size_t)(NRSEG+1)*4);
  int*   bsum   = (int*)  alloc(4096);           // DEDICATED (782*4 = 3128 B)
  int*   esrc   = (int*)  alloc((size_t)(EE+64)*4);
  u16*   WTf    = (u16*)  alloc((size_t)3*17*16384*2);
  u8*    xq     = (u8*)   alloc((size_t)NN*HD);
  u8*    h1q    = (u8*)   alloc((size_t)NN*HD);
  u8*    h2q    = (u8*)   alloc((size_t)NN*HD);
  u16*   h3     = (u16*)  alloc((size_t)NN*HD*2);
  int*   cnt    = (int*)h3;                      // dead before h3 writes

  const int* src_in = eidx;        // edge_index[0]
  const int* dst_in = eidx + EE;   // edge_index[1]

  const int nscan = (NRSEG + SCB - 1) / SCB;   // 782

  hipMemsetAsync(cnt, 0, (size_t)NRSEG*4, stream);
  k_quant_hist<<<EE/256, 256, 0, stream>>>(x, xq, flag, dst_in, etype, cnt);
  k_scan1  <<<nscan, SCB, 0, stream>>>(cnt, off, bsum);
  k_scan2  <<<1,    1024, 0, stream>>>(bsum, nscan);
  k_scatter<<<EE/256, 256, 0, stream>>>(src_in, dst_in, etype, off, bsum, cnt, esrc);

  k_weights3<<<3*1088, 256, 0, stream>>>(basesA[0], compA[0], rootA[0],
                                         basesA[1], compA[1], rootA[1],
                                         basesA[2], compA[2], rootA[2],
                                         WTf, flag);

  const int nblk = (NN + TN - 1) / TN;   // 1563 (tail block handles 16 nodes)
  u16* W0 = WTf;
  u16* W1 = WTf + (size_t)1*17*16384;
  u16* W2 = WTf + (size_t)2*17*16384;
  // layer 1: xq -> h1q (fp8)
  k_layer<<<nblk, 512, 0, stream>>>(xq,  W0, biasA[0], off, bsum, esrc, (u16*)0, h1q, flag, 0, 1);
  // layer 2: h1q -> h2q (fp8)
  k_layer<<<nblk, 512, 0, stream>>>(h1q, W1, biasA[1], off, bsum, esrc, (u16*)0, h2q, flag, 0, 1);
  // layer 3: h2q -> h3 (bf16, no relu)
  k_layer<<<nblk, 512, 0, stream>>>(h2q, W2, biasA[2], off, bsum, esrc, h3, (u8*)0, flag, 1, 0);

  k_pool_head<<<NG, 1024, 0, stream>>>(h3, batch, rlab, rel_emb, lin_w, lin_b,
                                       d_out, flag);
}